// Round 4
// baseline (3224.239 us; speedup 1.0000x reference)
//
#include <hip/hip_runtime.h>

#define NROWS 524288
#define NCH 128

typedef __attribute__((ext_vector_type(8))) short bf16x8;
typedef __attribute__((ext_vector_type(4))) float f32x4;

static __device__ __forceinline__ unsigned short f2bf_rne(float f) {
    unsigned u = __float_as_uint(f);
    return (unsigned short)((u + 0x7FFFu + ((u >> 16) & 1u)) >> 16);
}

// ---------------------------------------------------------------------------
// k_gram: G = X^T X via bf16 hi/lo split MFMA.  x = h + l, h = trunc-bf16(x),
// l = rne-bf16(x - h);  G ≈ H^T H + H^T L + L^T H (one fp32 accumulator).
// Staging uses NAMED registers + macros (no lambdas, no local arrays) so
// nothing can fall to scratch.
// ---------------------------------------------------------------------------
#define GCH 32       // rows (K) per chunk
#define GSTR 40      // u16 stride per column (32 + 8 pad; 80 B, 16-aligned)

static __device__ __forceinline__ bf16x8 ldfrag(const unsigned short* base, int c, int k0) {
    return *(const bf16x8*)(base + c * GSTR + k0);
}

// pack pair (x0 = row 2p, x1 = row 2p+1) of column c into hi/lo LDS planes
#define PACKW(buf, c, x0, x1, csacc) do {                                     \
    unsigned u0 = __float_as_uint(x0), u1 = __float_as_uint(x1);              \
    unsigned packH = (u0 >> 16) | (u1 & 0xFFFF0000u);                         \
    float l0_ = (x0) - __uint_as_float(u0 & 0xFFFF0000u);                     \
    float l1_ = (x1) - __uint_as_float(u1 & 0xFFFF0000u);                     \
    unsigned packL = (unsigned)f2bf_rne(l0_) | ((unsigned)f2bf_rne(l1_) << 16); \
    *(unsigned*)&XT[buf][0][(c) * GSTR + 2 * p] = packH;                      \
    *(unsigned*)&XT[buf][1][(c) * GSTR + 2 * p] = packL;                      \
    csacc += (x0) + (x1);                                                     \
} while (0)

#define LOADREGS(ci) do {                                                     \
    const float4* s4 = (const float4*)x + (size_t)((ci) * GCH + 2 * p) * 32 + cg * 2; \
    v0 = s4[0]; v1 = s4[1]; v2 = s4[32]; v3 = s4[33];                         \
} while (0)

#define CVTWRITE(buf) do {                                                    \
    PACKW(buf, cg * 8 + 0, v0.x, v2.x, cs0);                                  \
    PACKW(buf, cg * 8 + 1, v0.y, v2.y, cs1);                                  \
    PACKW(buf, cg * 8 + 2, v0.z, v2.z, cs2);                                  \
    PACKW(buf, cg * 8 + 3, v0.w, v2.w, cs3);                                  \
    PACKW(buf, cg * 8 + 4, v1.x, v3.x, cs4);                                  \
    PACKW(buf, cg * 8 + 5, v1.y, v3.y, cs5);                                  \
    PACKW(buf, cg * 8 + 6, v1.z, v3.z, cs6);                                  \
    PACKW(buf, cg * 8 + 7, v1.w, v3.w, cs7);                                  \
} while (0)

__global__ __launch_bounds__(256, 2) void k_gram(const float* __restrict__ x,
                                                 float* __restrict__ gram,
                                                 float* __restrict__ colsum) {
    __shared__ __align__(16) unsigned short XT[2][2][128 * GSTR];  // [buf][hi/lo]
    const int tid = threadIdx.x;
    const int w = tid >> 6;          // wave 0..3 -> tile rows {2w, 2w+1}
    const int l = tid & 63;
    const int lc = l & 15;           // fragment row/col within tile
    const int lk = (l >> 4) * 8;     // fragment k-offset
    const int p = tid & 15;          // staging: row-pair (rows 2p, 2p+1)
    const int cg = tid >> 4;         // staging: col-group (8 cols)

    f32x4 acc[2][8];
#pragma unroll
    for (int a = 0; a < 2; ++a)
#pragma unroll
        for (int t = 0; t < 8; ++t) acc[a][t] = (f32x4){0.f, 0.f, 0.f, 0.f};
    float cs0 = 0.f, cs1 = 0.f, cs2 = 0.f, cs3 = 0.f;
    float cs4 = 0.f, cs5 = 0.f, cs6 = 0.f, cs7 = 0.f;

    const int c0 = blockIdx.x * 32;  // 32 chunks per block, 512 blocks
    float4 v0, v1, v2, v3;

    LOADREGS(c0);
    CVTWRITE(0);
    __syncthreads();

    for (int i = 0; i < 32; ++i) {
        const int buf = i & 1;
        if (i + 1 < 32) LOADREGS(c0 + i + 1);

        const unsigned short* Xh = &XT[buf][0][0];
        const unsigned short* Xl = &XT[buf][1][0];
        bf16x8 ah[2], al[2];
#pragma unroll
        for (int a = 0; a < 2; ++a) {
            ah[a] = ldfrag(Xh, (2 * w + a) * 16 + lc, lk);
            al[a] = ldfrag(Xl, (2 * w + a) * 16 + lc, lk);
        }
#pragma unroll
        for (int tj = 0; tj < 8; ++tj) {
            bf16x8 bh = ldfrag(Xh, tj * 16 + lc, lk);
            bf16x8 bl = ldfrag(Xl, tj * 16 + lc, lk);
#pragma unroll
            for (int a = 0; a < 2; ++a) {
                acc[a][tj] = __builtin_amdgcn_mfma_f32_16x16x32_bf16(ah[a], bh, acc[a][tj], 0, 0, 0);
                acc[a][tj] = __builtin_amdgcn_mfma_f32_16x16x32_bf16(ah[a], bl, acc[a][tj], 0, 0, 0);
                acc[a][tj] = __builtin_amdgcn_mfma_f32_16x16x32_bf16(al[a], bh, acc[a][tj], 0, 0, 0);
            }
        }
        __syncthreads();
        if (i + 1 < 32) CVTWRITE(buf ^ 1);
        __syncthreads();
    }

#pragma unroll
    for (int a = 0; a < 2; ++a)
#pragma unroll
        for (int tj = 0; tj < 8; ++tj)
#pragma unroll
            for (int q = 0; q < 4; ++q) {
                int row = (2 * w + a) * 16 + (l >> 4) * 4 + q;
                int col = tj * 16 + lc;
                atomicAdd(&gram[row * NCH + col], acc[a][tj][q]);
            }
    atomicAdd(&colsum[cg * 8 + 0], cs0);
    atomicAdd(&colsum[cg * 8 + 1], cs1);
    atomicAdd(&colsum[cg * 8 + 2], cs2);
    atomicAdd(&colsum[cg * 8 + 3], cs3);
    atomicAdd(&colsum[cg * 8 + 4], cs4);
    atomicAdd(&colsum[cg * 8 + 5], cs5);
    atomicAdd(&colsum[cg * 8 + 6], cs6);
    atomicAdd(&colsum[cg * 8 + 7], cs7);
}

// ---------------------------------------------------------------------------
// k_chol: parallel Cholesky + triangular inverse (unchanged).
// ---------------------------------------------------------------------------
__global__ __launch_bounds__(256) void k_chol(const float* __restrict__ gram,
                                              const float* __restrict__ colsum,
                                              float* __restrict__ Wout,
                                              float* __restrict__ mout) {
    __shared__ float A[128][129];
    __shared__ float B[128][129];
    __shared__ float m[128];
    __shared__ float dsq[128];
    __shared__ float rd2[128];
    const int tid = threadIdx.x;

    if (tid < 128) {
        m[tid] = colsum[tid] * (1.0f / (float)NROWS);
        mout[tid] = m[tid];
    }
    __syncthreads();
    for (int idx = tid; idx < 128 * 128; idx += 256) {
        int i = idx >> 7, j = idx & 127;
        A[i][j] = (gram[idx] - (float)NROWS * m[i] * m[j]) * (1.0f / (float)(NROWS - 1));
        B[i][j] = (i == j) ? 1.0f : 0.0f;
    }

    const int q = tid >> 1;
    const int h = tid & 1;
    for (int k = 0; k < 127; ++k) {
        __syncthreads();
        float rd = 1.0f / A[k][k];
        int j = k + 1 + q;
        if (j < 128) {
            float fj = A[j][k] * rd;
            for (int i = k + 1 + h; i < 128; i += 2)
                A[j][i] -= fj * A[k][i];
        }
    }
    __syncthreads();
    if (tid < 128) {
        float d = A[tid][tid];
        dsq[tid] = 1.0f / sqrtf(d);
        rd2[tid] = 1.0f / d;
    }

    for (int r = 0; r < 127; ++r) {
        __syncthreads();
        int j = r + 1 + q;
        if (j < 128) {
            float f = A[j][r] * rd2[r];
            for (int c = h; c <= r; c += 2)
                B[j][c] -= f * B[r][c];
        }
    }
    __syncthreads();

    for (int idx = tid; idx < 128 * 128; idx += 256) {
        int j = idx >> 7, c = idx & 127;
        float vv = (c < j) ? B[j][c] * dsq[j] : ((c == j) ? dsq[j] : 0.0f);
        Wout[idx] = vv;
    }
}

// ---------------------------------------------------------------------------
// k_apply: out = xn + bf16(xn) @ R^T  where R = W - I (unchanged).
// ---------------------------------------------------------------------------
__global__ __launch_bounds__(256, 3) void k_apply(const float* __restrict__ x,
                                                  const float* __restrict__ Wg,
                                                  const float* __restrict__ mg,
                                                  float* __restrict__ out) {
    __shared__ __align__(16) unsigned char XS[128 * 128];  // 128 rows x 64 bf16, swizzled
    __shared__ float msh[128];
    const int tid = threadIdx.x;
    const int w = tid >> 6, l = tid & 63;
    const int lc = l & 15, la = l >> 4;

    if (tid < 32) *(float4*)&msh[tid * 4] = *(const float4*)&mg[tid * 4];
    __syncthreads();

    // R-fragments: wave w owns output-col tiles {2w, 2w+1}
    bf16x8 rfrag[2][4];
#pragma unroll
    for (int tjl = 0; tjl < 2; ++tjl) {
        int j = (w * 2 + tjl) * 16 + lc;
#pragma unroll
        for (int ks = 0; ks < 4; ++ks) {
            int i0 = ks * 32 + la * 8;
            float4 wa = *(const float4*)&Wg[j * 128 + i0];
            float4 wb = *(const float4*)&Wg[j * 128 + i0 + 4];
            rfrag[tjl][ks][0] = f2bf_rne(wa.x - ((j == i0 + 0) ? 1.0f : 0.0f));
            rfrag[tjl][ks][1] = f2bf_rne(wa.y - ((j == i0 + 1) ? 1.0f : 0.0f));
            rfrag[tjl][ks][2] = f2bf_rne(wa.z - ((j == i0 + 2) ? 1.0f : 0.0f));
            rfrag[tjl][ks][3] = f2bf_rne(wa.w - ((j == i0 + 3) ? 1.0f : 0.0f));
            rfrag[tjl][ks][4] = f2bf_rne(wb.x - ((j == i0 + 4) ? 1.0f : 0.0f));
            rfrag[tjl][ks][5] = f2bf_rne(wb.y - ((j == i0 + 5) ? 1.0f : 0.0f));
            rfrag[tjl][ks][6] = f2bf_rne(wb.z - ((j == i0 + 6) ? 1.0f : 0.0f));
            rfrag[tjl][ks][7] = f2bf_rne(wb.w - ((j == i0 + 7) ? 1.0f : 0.0f));
        }
    }

    f32x4 acc[8][2];
#pragma unroll
    for (int ti = 0; ti < 8; ++ti)
#pragma unroll
        for (int tjl = 0; tjl < 2; ++tjl) acc[ti][tjl] = (f32x4){0.f, 0.f, 0.f, 0.f};

    const size_t rowbase = (size_t)blockIdx.x * 128;

#pragma unroll
    for (int c = 0; c < 2; ++c) {
        const int kb = c * 64;
#pragma unroll
        for (int rep = 0; rep < 8; ++rep) {
            int f = tid + 256 * rep;
            int r = f >> 4, i4 = f & 15;
            float4 vx = *(const float4*)&x[(rowbase + r) * 128 + kb + i4 * 4];
            float4 mv = *(const float4*)&msh[kb + i4 * 4];
            unsigned b0 = f2bf_rne(vx.x - mv.x);
            unsigned b1 = f2bf_rne(vx.y - mv.y);
            unsigned b2 = f2bf_rne(vx.z - mv.z);
            unsigned b3 = f2bf_rne(vx.w - mv.w);
            unsigned off = r * 128 + ((((i4 >> 1) ^ (r & 7))) << 4) + (i4 & 1) * 8;
            *(uint2*)(XS + off) = make_uint2(b0 | (b1 << 16), b2 | (b3 << 16));
        }
        __syncthreads();
#pragma unroll
        for (int ksl = 0; ksl < 2; ++ksl) {
#pragma unroll
            for (int ti = 0; ti < 8; ++ti) {
                int r = ti * 16 + lc;
                int g = ksl * 4 + la;
                bf16x8 af = *(const bf16x8*)(XS + r * 128 + ((g ^ (r & 7)) << 4));
                acc[ti][0] = __builtin_amdgcn_mfma_f32_16x16x32_bf16(af, rfrag[0][c * 2 + ksl], acc[ti][0], 0, 0, 0);
                acc[ti][1] = __builtin_amdgcn_mfma_f32_16x16x32_bf16(af, rfrag[1][c * 2 + ksl], acc[ti][1], 0, 0, 0);
            }
        }
        __syncthreads();
    }

    // epilogue: out = (x - m) + acc   (x reload is an L2 hit: same tile)
#pragma unroll
    for (int ti = 0; ti < 8; ++ti)
#pragma unroll
        for (int tjl = 0; tjl < 2; ++tjl)
#pragma unroll
            for (int q = 0; q < 4; ++q) {
                int rloc = ti * 16 + la * 4 + q;
                int cglob = (w * 2 + tjl) * 16 + lc;
                size_t a = (rowbase + rloc) * 128 + cglob;
                out[a] = (x[a] - msh[cglob]) + acc[ti][tjl][q];
            }
}

extern "C" void kernel_launch(void* const* d_in, const int* in_sizes, int n_in,
                              void* d_out, int out_size, void* d_ws, size_t ws_size,
                              hipStream_t stream) {
    const float* x = (const float*)d_in[0];
    float* ws = (float*)d_ws;
    float* gram = ws;              // 16384
    float* colsum = ws + 16384;    // 128
    float* W = ws + 16512;         // 16384
    float* m = ws + 32896;         // 128
    float* out = (float*)d_out;

    hipMemsetAsync(d_ws, 0, (16384 + 128) * sizeof(float), stream);
    k_gram<<<512, 256, 0, stream>>>(x, gram, colsum);
    k_chol<<<1, 256, 0, stream>>>(gram, colsum, W, m);
    k_apply<<<NROWS / 128, 256, 0, stream>>>(x, W, m, out);
}

// Round 5
// 2010.153 us; speedup vs baseline: 1.6040x; 1.6040x over previous
//
#include <hip/hip_runtime.h>

#define NROWS 524288
#define NCH 128

typedef __attribute__((ext_vector_type(8))) short bf16x8;
typedef __attribute__((ext_vector_type(4))) float f32x4;

static __device__ __forceinline__ unsigned short f2bf_rne(float f) {
    unsigned u = __float_as_uint(f);
    return (unsigned short)((u + 0x7FFFu + ((u >> 16) & 1u)) >> 16);
}

// ---------------------------------------------------------------------------
// k_gram: G2 = H^T H + H^T (2L) via bf16 MFMA, where x = h + l,
// h = trunc-bf16(x), l = rne-bf16(x-h).  k_chol symmetrizes:
// sym(G2) = H^T H + H^T L + L^T H  (exact).
// Phase structure per 32-row chunk (k_apply-proven template, NO register
// state carried across barriers):  barrier; stage (coalesced load -> pack ->
// swizzled LDS store); barrier; MFMA accumulate.
// LDS: XT[plane][ch*GSTR + 2*(slot ^ ((ch>>3)&12)) + (k&1)], GSTR=40 u16.
// slot = k>>1.  Swizzle mask &12 keeps 16B frag reads contiguous.
// ---------------------------------------------------------------------------
#define GSTR 40

static __device__ __forceinline__ bf16x8 ldfrag(const unsigned short* base, int c, int s0) {
    int m = (c >> 3) & 12;
    return *(const bf16x8*)(base + c * GSTR + 2 * (s0 ^ m));
}

// pack rows (2p, 2p+1) of channel c; x0 = row 2p, x1 = row 2p+1
#define PACKW(c, x0, x1, csacc) do {                                          \
    unsigned u0 = __float_as_uint(x0), u1 = __float_as_uint(x1);              \
    unsigned packH = (u0 >> 16) | (u1 & 0xFFFF0000u);                         \
    float l0_ = 2.0f * ((x0) - __uint_as_float(u0 & 0xFFFF0000u));            \
    float l1_ = 2.0f * ((x1) - __uint_as_float(u1 & 0xFFFF0000u));            \
    unsigned packL = (unsigned)f2bf_rne(l0_) | ((unsigned)f2bf_rne(l1_) << 16); \
    int idx_ = (c) * GSTR + 2 * (p ^ (cg & 12));                              \
    *(unsigned*)&XT[0][idx_] = packH;                                         \
    *(unsigned*)&XT[1][idx_] = packL;                                         \
    csacc += (x0) + (x1);                                                     \
} while (0)

__global__ __launch_bounds__(256) void k_gram(const float* __restrict__ x,
                                              float* __restrict__ gram,
                                              float* __restrict__ colsum) {
    __shared__ __align__(16) unsigned short XT[2][128 * GSTR];  // hi / 2*lo planes
    const int tid = threadIdx.x;
    const int w = tid >> 6;          // wave -> tile rows {2w, 2w+1}
    const int l = tid & 63;
    const int lc = l & 15;
    const int ls = (l >> 4) * 4;     // 4B k-slot base of fragment
    const int p = tid >> 4;          // staging: row-pair (rows 2p, 2p+1)
    const int cg = tid & 15;         // staging: col-group (8 ch) -> lane-minor: coalesced

    f32x4 acc[2][8];
#pragma unroll
    for (int a = 0; a < 2; ++a)
#pragma unroll
        for (int t = 0; t < 8; ++t) acc[a][t] = (f32x4){0.f, 0.f, 0.f, 0.f};
    float cs0 = 0.f, cs1 = 0.f, cs2 = 0.f, cs3 = 0.f;
    float cs4 = 0.f, cs5 = 0.f, cs6 = 0.f, cs7 = 0.f;

    const size_t row0 = (size_t)blockIdx.x * 1024;   // 512 blocks x 1024 rows

    for (int i = 0; i < 32; ++i) {
        __syncthreads();             // previous chunk's frag reads done
        {
            const float4* s4 = (const float4*)x + (row0 + i * 32 + 2 * p) * 32 + cg * 2;
            float4 v0 = s4[0], v1 = s4[1];     // row 2p,   ch cg*8..+7
            float4 v2 = s4[32], v3 = s4[33];   // row 2p+1
            PACKW(cg * 8 + 0, v0.x, v2.x, cs0);
            PACKW(cg * 8 + 1, v0.y, v2.y, cs1);
            PACKW(cg * 8 + 2, v0.z, v2.z, cs2);
            PACKW(cg * 8 + 3, v0.w, v2.w, cs3);
            PACKW(cg * 8 + 4, v1.x, v3.x, cs4);
            PACKW(cg * 8 + 5, v1.y, v3.y, cs5);
            PACKW(cg * 8 + 6, v1.z, v3.z, cs6);
            PACKW(cg * 8 + 7, v1.w, v3.w, cs7);
        }
        __syncthreads();

        const unsigned short* Xh = &XT[0][0];
        const unsigned short* Xl = &XT[1][0];
        bf16x8 ah0 = ldfrag(Xh, (2 * w + 0) * 16 + lc, ls);
        bf16x8 ah1 = ldfrag(Xh, (2 * w + 1) * 16 + lc, ls);
#pragma unroll
        for (int tj = 0; tj < 8; ++tj) {
            bf16x8 bh = ldfrag(Xh, tj * 16 + lc, ls);
            bf16x8 bl = ldfrag(Xl, tj * 16 + lc, ls);
            acc[0][tj] = __builtin_amdgcn_mfma_f32_16x16x32_bf16(ah0, bh, acc[0][tj], 0, 0, 0);
            acc[0][tj] = __builtin_amdgcn_mfma_f32_16x16x32_bf16(ah0, bl, acc[0][tj], 0, 0, 0);
            acc[1][tj] = __builtin_amdgcn_mfma_f32_16x16x32_bf16(ah1, bh, acc[1][tj], 0, 0, 0);
            acc[1][tj] = __builtin_amdgcn_mfma_f32_16x16x32_bf16(ah1, bl, acc[1][tj], 0, 0, 0);
        }
    }

#pragma unroll
    for (int a = 0; a < 2; ++a)
#pragma unroll
        for (int tj = 0; tj < 8; ++tj)
#pragma unroll
            for (int q = 0; q < 4; ++q) {
                int row = (2 * w + a) * 16 + (l >> 4) * 4 + q;
                int col = tj * 16 + lc;
                atomicAdd(&gram[row * NCH + col], acc[a][tj][q]);
            }
    atomicAdd(&colsum[cg * 8 + 0], cs0);
    atomicAdd(&colsum[cg * 8 + 1], cs1);
    atomicAdd(&colsum[cg * 8 + 2], cs2);
    atomicAdd(&colsum[cg * 8 + 3], cs3);
    atomicAdd(&colsum[cg * 8 + 4], cs4);
    atomicAdd(&colsum[cg * 8 + 5], cs5);
    atomicAdd(&colsum[cg * 8 + 6], cs6);
    atomicAdd(&colsum[cg * 8 + 7], cs7);
}

// ---------------------------------------------------------------------------
// k_chol: symmetrize G2, then parallel Cholesky + triangular inverse.
// ---------------------------------------------------------------------------
__global__ __launch_bounds__(256) void k_chol(const float* __restrict__ gram,
                                              const float* __restrict__ colsum,
                                              float* __restrict__ Wout,
                                              float* __restrict__ mout) {
    __shared__ float A[128][129];
    __shared__ float B[128][129];
    __shared__ float m[128];
    __shared__ float dsq[128];
    __shared__ float rd2[128];
    const int tid = threadIdx.x;

    if (tid < 128) {
        m[tid] = colsum[tid] * (1.0f / (float)NROWS);
        mout[tid] = m[tid];
    }
    __syncthreads();
    for (int idx = tid; idx < 128 * 128; idx += 256) {
        int i = idx >> 7, j = idx & 127;
        float g = 0.5f * (gram[i * NCH + j] + gram[j * NCH + i]);   // sym(G2)
        A[i][j] = (g - (float)NROWS * m[i] * m[j]) * (1.0f / (float)(NROWS - 1));
        B[i][j] = (i == j) ? 1.0f : 0.0f;
    }

    const int q = tid >> 1;
    const int h = tid & 1;
    for (int k = 0; k < 127; ++k) {
        __syncthreads();
        float rd = 1.0f / A[k][k];
        int j = k + 1 + q;
        if (j < 128) {
            float fj = A[j][k] * rd;
            for (int i = k + 1 + h; i < 128; i += 2)
                A[j][i] -= fj * A[k][i];
        }
    }
    __syncthreads();
    if (tid < 128) {
        float d = A[tid][tid];
        dsq[tid] = 1.0f / sqrtf(d);
        rd2[tid] = 1.0f / d;
    }

    for (int r = 0; r < 127; ++r) {
        __syncthreads();
        int j = r + 1 + q;
        if (j < 128) {
            float f = A[j][r] * rd2[r];
            for (int c = h; c <= r; c += 2)
                B[j][c] -= f * B[r][c];
        }
    }
    __syncthreads();

    for (int idx = tid; idx < 128 * 128; idx += 256) {
        int j = idx >> 7, c = idx & 127;
        float vv = (c < j) ? B[j][c] * dsq[j] : ((c == j) ? dsq[j] : 0.0f);
        Wout[idx] = vv;
    }
}

// ---------------------------------------------------------------------------
// k_apply: out = xn + bf16(xn) @ R^T  where R = W - I (unchanged, healthy).
// ---------------------------------------------------------------------------
__global__ __launch_bounds__(256, 3) void k_apply(const float* __restrict__ x,
                                                  const float* __restrict__ Wg,
                                                  const float* __restrict__ mg,
                                                  float* __restrict__ out) {
    __shared__ __align__(16) unsigned char XS[128 * 128];  // 128 rows x 64 bf16, swizzled
    __shared__ float msh[128];
    const int tid = threadIdx.x;
    const int w = tid >> 6, l = tid & 63;
    const int lc = l & 15, la = l >> 4;

    if (tid < 32) *(float4*)&msh[tid * 4] = *(const float4*)&mg[tid * 4];
    __syncthreads();

    bf16x8 rfrag[2][4];
#pragma unroll
    for (int tjl = 0; tjl < 2; ++tjl) {
        int j = (w * 2 + tjl) * 16 + lc;
#pragma unroll
        for (int ks = 0; ks < 4; ++ks) {
            int i0 = ks * 32 + la * 8;
            float4 wa = *(const float4*)&Wg[j * 128 + i0];
            float4 wb = *(const float4*)&Wg[j * 128 + i0 + 4];
            rfrag[tjl][ks][0] = f2bf_rne(wa.x - ((j == i0 + 0) ? 1.0f : 0.0f));
            rfrag[tjl][ks][1] = f2bf_rne(wa.y - ((j == i0 + 1) ? 1.0f : 0.0f));
            rfrag[tjl][ks][2] = f2bf_rne(wa.z - ((j == i0 + 2) ? 1.0f : 0.0f));
            rfrag[tjl][ks][3] = f2bf_rne(wa.w - ((j == i0 + 3) ? 1.0f : 0.0f));
            rfrag[tjl][ks][4] = f2bf_rne(wb.x - ((j == i0 + 4) ? 1.0f : 0.0f));
            rfrag[tjl][ks][5] = f2bf_rne(wb.y - ((j == i0 + 5) ? 1.0f : 0.0f));
            rfrag[tjl][ks][6] = f2bf_rne(wb.z - ((j == i0 + 6) ? 1.0f : 0.0f));
            rfrag[tjl][ks][7] = f2bf_rne(wb.w - ((j == i0 + 7) ? 1.0f : 0.0f));
        }
    }

    f32x4 acc[8][2];
#pragma unroll
    for (int ti = 0; ti < 8; ++ti)
#pragma unroll
        for (int tjl = 0; tjl < 2; ++tjl) acc[ti][tjl] = (f32x4){0.f, 0.f, 0.f, 0.f};

    const size_t rowbase = (size_t)blockIdx.x * 128;

#pragma unroll
    for (int c = 0; c < 2; ++c) {
        const int kb = c * 64;
#pragma unroll
        for (int rep = 0; rep < 8; ++rep) {
            int f = tid + 256 * rep;
            int r = f >> 4, i4 = f & 15;
            float4 vx = *(const float4*)&x[(rowbase + r) * 128 + kb + i4 * 4];
            float4 mv = *(const float4*)&msh[kb + i4 * 4];
            unsigned b0 = f2bf_rne(vx.x - mv.x);
            unsigned b1 = f2bf_rne(vx.y - mv.y);
            unsigned b2 = f2bf_rne(vx.z - mv.z);
            unsigned b3 = f2bf_rne(vx.w - mv.w);
            unsigned off = r * 128 + ((((i4 >> 1) ^ (r & 7))) << 4) + (i4 & 1) * 8;
            *(uint2*)(XS + off) = make_uint2(b0 | (b1 << 16), b2 | (b3 << 16));
        }
        __syncthreads();
#pragma unroll
        for (int ksl = 0; ksl < 2; ++ksl) {
#pragma unroll
            for (int ti = 0; ti < 8; ++ti) {
                int r = ti * 16 + lc;
                int g = ksl * 4 + la;
                bf16x8 af = *(const bf16x8*)(XS + r * 128 + ((g ^ (r & 7)) << 4));
                acc[ti][0] = __builtin_amdgcn_mfma_f32_16x16x32_bf16(af, rfrag[0][c * 2 + ksl], acc[ti][0], 0, 0, 0);
                acc[ti][1] = __builtin_amdgcn_mfma_f32_16x16x32_bf16(af, rfrag[1][c * 2 + ksl], acc[ti][1], 0, 0, 0);
            }
        }
        __syncthreads();
    }

#pragma unroll
    for (int ti = 0; ti < 8; ++ti)
#pragma unroll
        for (int tjl = 0; tjl < 2; ++tjl)
#pragma unroll
            for (int q = 0; q < 4; ++q) {
                int rloc = ti * 16 + la * 4 + q;
                int cglob = (w * 2 + tjl) * 16 + lc;
                size_t a = (rowbase + rloc) * 128 + cglob;
                out[a] = (x[a] - msh[cglob]) + acc[ti][tjl][q];
            }
}

extern "C" void kernel_launch(void* const* d_in, const int* in_sizes, int n_in,
                              void* d_out, int out_size, void* d_ws, size_t ws_size,
                              hipStream_t stream) {
    const float* x = (const float*)d_in[0];
    float* ws = (float*)d_ws;
    float* gram = ws;              // 16384
    float* colsum = ws + 16384;    // 128
    float* W = ws + 16512;         // 16384
    float* m = ws + 32896;         // 128
    float* out = (float*)d_out;

    hipMemsetAsync(d_ws, 0, (16384 + 128) * sizeof(float), stream);
    k_gram<<<512, 256, 0, stream>>>(x, gram, colsum);
    k_chol<<<1, 256, 0, stream>>>(gram, colsum, W, m);
    k_apply<<<NROWS / 128, 256, 0, stream>>>(x, W, m, out);
}

// Round 6
// 672.405 us; speedup vs baseline: 4.7951x; 2.9895x over previous
//
#include <hip/hip_runtime.h>

#define NROWS 524288
#define NCH 128
#define GSTR 40

typedef __attribute__((ext_vector_type(8))) short bf16x8;
typedef __attribute__((ext_vector_type(4))) float f32x4;

static __device__ __forceinline__ unsigned short f2bf_rne(float f) {
    unsigned u = __float_as_uint(f);
    return (unsigned short)((u + 0x7FFFu + ((u >> 16) & 1u)) >> 16);
}

static __device__ __forceinline__ bf16x8 ldfrag(const unsigned short* base, int c, int s0) {
    int m = (c >> 3) & 12;
    return *(const bf16x8*)(base + c * GSTR + 2 * (s0 ^ m));
}

// ---------------------------------------------------------------------------
// k_gram: G2 = H^T H + H^T (2L), x = h + l (hi/lo bf16 split); k_chol
// symmetrizes sym(G2) = H^T H + H^T L + L^T H exactly.
// Pipeline: depth-2 register prefetch (reg sets A/B) + double-buffered LDS,
// ONE barrier per chunk.  Epilogue: plain-store partials (STORE=1) or
// atomicAdd fallback (STORE=0) when ws is too small.
// ---------------------------------------------------------------------------
#define PACKW1(B, c, x0, x1, csacc) do {                                      \
    unsigned u0 = __float_as_uint(x0), u1 = __float_as_uint(x1);              \
    unsigned packH = (u0 >> 16) | (u1 & 0xFFFF0000u);                         \
    float l0_ = 2.0f * ((x0) - __uint_as_float(u0 & 0xFFFF0000u));            \
    float l1_ = 2.0f * ((x1) - __uint_as_float(u1 & 0xFFFF0000u));            \
    unsigned packL = (unsigned)f2bf_rne(l0_) | ((unsigned)f2bf_rne(l1_) << 16); \
    int idx_ = (c) * GSTR + 2 * (p ^ (cg & 12));                              \
    *(unsigned*)&XT[B][0][idx_] = packH;                                      \
    *(unsigned*)&XT[B][1][idx_] = packL;                                      \
    csacc += (x0) + (x1);                                                     \
} while (0)

#define LOADR(ci, r0, r1, r2, r3) do {                                        \
    const float4* s4_ = (const float4*)x + ((size_t)(ci) * 32 + 2 * p) * 32 + cg * 2; \
    r0 = s4_[0]; r1 = s4_[1]; r2 = s4_[32]; r3 = s4_[33];                     \
} while (0)

#define PACKALL(B, r0, r1, r2, r3) do {                                       \
    PACKW1(B, cg * 8 + 0, r0.x, r2.x, cs0);                                   \
    PACKW1(B, cg * 8 + 1, r0.y, r2.y, cs1);                                   \
    PACKW1(B, cg * 8 + 2, r0.z, r2.z, cs2);                                   \
    PACKW1(B, cg * 8 + 3, r0.w, r2.w, cs3);                                   \
    PACKW1(B, cg * 8 + 4, r1.x, r3.x, cs4);                                   \
    PACKW1(B, cg * 8 + 5, r1.y, r3.y, cs5);                                   \
    PACKW1(B, cg * 8 + 6, r1.z, r3.z, cs6);                                   \
    PACKW1(B, cg * 8 + 7, r1.w, r3.w, cs7);                                   \
} while (0)

#define MFMA_STEP(B) do {                                                     \
    const unsigned short* Xh = &XT[B][0][0];                                  \
    const unsigned short* Xl = &XT[B][1][0];                                  \
    bf16x8 ah0 = ldfrag(Xh, (2 * w + 0) * 16 + lc, ls);                       \
    bf16x8 ah1 = ldfrag(Xh, (2 * w + 1) * 16 + lc, ls);                       \
    _Pragma("unroll")                                                         \
    for (int tj = 0; tj < 8; ++tj) {                                          \
        bf16x8 bh = ldfrag(Xh, tj * 16 + lc, ls);                             \
        bf16x8 bl = ldfrag(Xl, tj * 16 + lc, ls);                             \
        acc[0][tj] = __builtin_amdgcn_mfma_f32_16x16x32_bf16(ah0, bh, acc[0][tj], 0, 0, 0); \
        acc[0][tj] = __builtin_amdgcn_mfma_f32_16x16x32_bf16(ah0, bl, acc[0][tj], 0, 0, 0); \
        acc[1][tj] = __builtin_amdgcn_mfma_f32_16x16x32_bf16(ah1, bh, acc[1][tj], 0, 0, 0); \
        acc[1][tj] = __builtin_amdgcn_mfma_f32_16x16x32_bf16(ah1, bl, acc[1][tj], 0, 0, 0); \
    }                                                                         \
} while (0)

template <int STORE>
__global__ __launch_bounds__(256, 3) void k_gram(const float* __restrict__ x,
                                                 float* __restrict__ part,
                                                 float* __restrict__ colpart,
                                                 float* __restrict__ gram,
                                                 float* __restrict__ colsum,
                                                 int cpb) {
    __shared__ __align__(16) unsigned short XT[2][2][128 * GSTR];  // [buf][hi/lo]
    const int tid = threadIdx.x;
    const int w = tid >> 6;
    const int l = tid & 63;
    const int lc = l & 15;
    const int ls = (l >> 4) * 4;
    const int p = tid >> 4;          // row-pair (rows 2p,2p+1 of chunk)
    const int cg = tid & 15;         // channel-group (8 ch), lane-minor

    f32x4 acc[2][8];
#pragma unroll
    for (int a = 0; a < 2; ++a)
#pragma unroll
        for (int t = 0; t < 8; ++t) acc[a][t] = (f32x4){0.f, 0.f, 0.f, 0.f};
    float cs0 = 0.f, cs1 = 0.f, cs2 = 0.f, cs3 = 0.f;
    float cs4 = 0.f, cs5 = 0.f, cs6 = 0.f, cs7 = 0.f;

    const int c0 = blockIdx.x * cpb;
    float4 a0, a1, a2, a3, b0, b1, b2, b3;

    LOADR(c0 + 0, a0, a1, a2, a3);
    LOADR(c0 + 1, b0, b1, b2, b3);
    PACKALL(0, a0, a1, a2, a3);
    __syncthreads();

#pragma unroll 1
    for (int t = 0; t < cpb; t += 2) {
        MFMA_STEP(0);                         // chunk t
        PACKALL(1, b0, b1, b2, b3);           // chunk t+1 -> LDS[1]
        if (t + 2 < cpb) LOADR(c0 + t + 2, a0, a1, a2, a3);
        __syncthreads();
        MFMA_STEP(1);                         // chunk t+1
        if (t + 2 < cpb) {
            PACKALL(0, a0, a1, a2, a3);       // chunk t+2 -> LDS[0]
            if (t + 3 < cpb) LOADR(c0 + t + 3, b0, b1, b2, b3);
            __syncthreads();
        }
    }

    // intra-block colsum reduction (reuse XT as float LDS)
    __syncthreads();
    float* cls = (float*)&XT[0][0][0];        // 128 ch x 16 pairs
    cls[(cg * 8 + 0) * 16 + p] = cs0;
    cls[(cg * 8 + 1) * 16 + p] = cs1;
    cls[(cg * 8 + 2) * 16 + p] = cs2;
    cls[(cg * 8 + 3) * 16 + p] = cs3;
    cls[(cg * 8 + 4) * 16 + p] = cs4;
    cls[(cg * 8 + 5) * 16 + p] = cs5;
    cls[(cg * 8 + 6) * 16 + p] = cs6;
    cls[(cg * 8 + 7) * 16 + p] = cs7;
    __syncthreads();
    float csr = 0.f;
    if (tid < 128) {
#pragma unroll
        for (int pp = 0; pp < 16; ++pp) csr += cls[tid * 16 + pp];
    }

    if (STORE) {
        float* pb = part + (size_t)blockIdx.x * 16384;
#pragma unroll
        for (int a = 0; a < 2; ++a)
#pragma unroll
            for (int tj = 0; tj < 8; ++tj)
#pragma unroll
                for (int q = 0; q < 4; ++q) {
                    int row = (2 * w + a) * 16 + (l >> 4) * 4 + q;
                    int col = tj * 16 + lc;
                    pb[row * NCH + col] = acc[a][tj][q];
                }
        if (tid < 128) colpart[blockIdx.x * 128 + tid] = csr;
    } else {
#pragma unroll
        for (int a = 0; a < 2; ++a)
#pragma unroll
            for (int tj = 0; tj < 8; ++tj)
#pragma unroll
                for (int q = 0; q < 4; ++q) {
                    int row = (2 * w + a) * 16 + (l >> 4) * 4 + q;
                    int col = tj * 16 + lc;
                    atomicAdd(&gram[row * NCH + col], acc[a][tj][q]);
                }
        if (tid < 128) atomicAdd(&colsum[tid], csr);
    }
}

__global__ __launch_bounds__(256) void k_reduce(const float* __restrict__ part,
                                                const float* __restrict__ colpart,
                                                float* __restrict__ gram,
                                                float* __restrict__ colsum,
                                                int nP) {
    const int tid = threadIdx.x;
    if (blockIdx.x < 64) {
        const int e = blockIdx.x * 256 + tid;
        float s = 0.f;
        for (int b = 0; b < nP; ++b) s += part[(size_t)b * 16384 + e];
        gram[e] = s;
    } else if (tid < 128) {
        float s = 0.f;
        for (int b = 0; b < nP; ++b) s += colpart[b * 128 + tid];
        colsum[tid] = s;
    }
}

// ---------------------------------------------------------------------------
// k_chol: symmetrize G2, parallel Cholesky + triangular inverse (unchanged).
// ---------------------------------------------------------------------------
__global__ __launch_bounds__(256) void k_chol(const float* __restrict__ gram,
                                              const float* __restrict__ colsum,
                                              float* __restrict__ Wout,
                                              float* __restrict__ mout) {
    __shared__ float A[128][129];
    __shared__ float B[128][129];
    __shared__ float m[128];
    __shared__ float dsq[128];
    __shared__ float rd2[128];
    const int tid = threadIdx.x;

    if (tid < 128) {
        m[tid] = colsum[tid] * (1.0f / (float)NROWS);
        mout[tid] = m[tid];
    }
    __syncthreads();
    for (int idx = tid; idx < 128 * 128; idx += 256) {
        int i = idx >> 7, j = idx & 127;
        float g = 0.5f * (gram[i * NCH + j] + gram[j * NCH + i]);   // sym(G2)
        A[i][j] = (g - (float)NROWS * m[i] * m[j]) * (1.0f / (float)(NROWS - 1));
        B[i][j] = (i == j) ? 1.0f : 0.0f;
    }

    const int q = tid >> 1;
    const int h = tid & 1;
    for (int k = 0; k < 127; ++k) {
        __syncthreads();
        float rd = 1.0f / A[k][k];
        int j = k + 1 + q;
        if (j < 128) {
            float fj = A[j][k] * rd;
            for (int i = k + 1 + h; i < 128; i += 2)
                A[j][i] -= fj * A[k][i];
        }
    }
    __syncthreads();
    if (tid < 128) {
        float d = A[tid][tid];
        dsq[tid] = 1.0f / sqrtf(d);
        rd2[tid] = 1.0f / d;
    }

    for (int r = 0; r < 127; ++r) {
        __syncthreads();
        int j = r + 1 + q;
        if (j < 128) {
            float f = A[j][r] * rd2[r];
            for (int c = h; c <= r; c += 2)
                B[j][c] -= f * B[r][c];
        }
    }
    __syncthreads();

    for (int idx = tid; idx < 128 * 128; idx += 256) {
        int j = idx >> 7, c = idx & 127;
        float vv = (c < j) ? B[j][c] * dsq[j] : ((c == j) ? dsq[j] : 0.0f);
        Wout[idx] = vv;
    }
}

// ---------------------------------------------------------------------------
// k_apply: out = xn + bf16(xn) @ R^T, R = W - I (unchanged, healthy).
// ---------------------------------------------------------------------------
__global__ __launch_bounds__(256, 3) void k_apply(const float* __restrict__ x,
                                                  const float* __restrict__ Wg,
                                                  const float* __restrict__ mg,
                                                  float* __restrict__ out) {
    __shared__ __align__(16) unsigned char XS[128 * 128];
    __shared__ float msh[128];
    const int tid = threadIdx.x;
    const int w = tid >> 6, l = tid & 63;
    const int lc = l & 15, la = l >> 4;

    if (tid < 32) *(float4*)&msh[tid * 4] = *(const float4*)&mg[tid * 4];
    __syncthreads();

    bf16x8 rfrag[2][4];
#pragma unroll
    for (int tjl = 0; tjl < 2; ++tjl) {
        int j = (w * 2 + tjl) * 16 + lc;
#pragma unroll
        for (int ks = 0; ks < 4; ++ks) {
            int i0 = ks * 32 + la * 8;
            float4 wa = *(const float4*)&Wg[j * 128 + i0];
            float4 wb = *(const float4*)&Wg[j * 128 + i0 + 4];
            rfrag[tjl][ks][0] = f2bf_rne(wa.x - ((j == i0 + 0) ? 1.0f : 0.0f));
            rfrag[tjl][ks][1] = f2bf_rne(wa.y - ((j == i0 + 1) ? 1.0f : 0.0f));
            rfrag[tjl][ks][2] = f2bf_rne(wa.z - ((j == i0 + 2) ? 1.0f : 0.0f));
            rfrag[tjl][ks][3] = f2bf_rne(wa.w - ((j == i0 + 3) ? 1.0f : 0.0f));
            rfrag[tjl][ks][4] = f2bf_rne(wb.x - ((j == i0 + 4) ? 1.0f : 0.0f));
            rfrag[tjl][ks][5] = f2bf_rne(wb.y - ((j == i0 + 5) ? 1.0f : 0.0f));
            rfrag[tjl][ks][6] = f2bf_rne(wb.z - ((j == i0 + 6) ? 1.0f : 0.0f));
            rfrag[tjl][ks][7] = f2bf_rne(wb.w - ((j == i0 + 7) ? 1.0f : 0.0f));
        }
    }

    f32x4 acc[8][2];
#pragma unroll
    for (int ti = 0; ti < 8; ++ti)
#pragma unroll
        for (int tjl = 0; tjl < 2; ++tjl) acc[ti][tjl] = (f32x4){0.f, 0.f, 0.f, 0.f};

    const size_t rowbase = (size_t)blockIdx.x * 128;

#pragma unroll
    for (int c = 0; c < 2; ++c) {
        const int kb = c * 64;
#pragma unroll
        for (int rep = 0; rep < 8; ++rep) {
            int f = tid + 256 * rep;
            int r = f >> 4, i4 = f & 15;
            float4 vx = *(const float4*)&x[(rowbase + r) * 128 + kb + i4 * 4];
            float4 mv = *(const float4*)&msh[kb + i4 * 4];
            unsigned b0 = f2bf_rne(vx.x - mv.x);
            unsigned b1 = f2bf_rne(vx.y - mv.y);
            unsigned b2 = f2bf_rne(vx.z - mv.z);
            unsigned b3 = f2bf_rne(vx.w - mv.w);
            unsigned off = r * 128 + ((((i4 >> 1) ^ (r & 7))) << 4) + (i4 & 1) * 8;
            *(uint2*)(XS + off) = make_uint2(b0 | (b1 << 16), b2 | (b3 << 16));
        }
        __syncthreads();
#pragma unroll
        for (int ksl = 0; ksl < 2; ++ksl) {
#pragma unroll
            for (int ti = 0; ti < 8; ++ti) {
                int r = ti * 16 + lc;
                int g = ksl * 4 + la;
                bf16x8 af = *(const bf16x8*)(XS + r * 128 + ((g ^ (r & 7)) << 4));
                acc[ti][0] = __builtin_amdgcn_mfma_f32_16x16x32_bf16(af, rfrag[0][c * 2 + ksl], acc[ti][0], 0, 0, 0);
                acc[ti][1] = __builtin_amdgcn_mfma_f32_16x16x32_bf16(af, rfrag[1][c * 2 + ksl], acc[ti][1], 0, 0, 0);
            }
        }
        __syncthreads();
    }

#pragma unroll
    for (int ti = 0; ti < 8; ++ti)
#pragma unroll
        for (int tjl = 0; tjl < 2; ++tjl)
#pragma unroll
            for (int q = 0; q < 4; ++q) {
                int rloc = ti * 16 + la * 4 + q;
                int cglob = (w * 2 + tjl) * 16 + lc;
                size_t a = (rowbase + rloc) * 128 + cglob;
                out[a] = (x[a] - msh[cglob]) + acc[ti][tjl][q];
            }
}

extern "C" void kernel_launch(void* const* d_in, const int* in_sizes, int n_in,
                              void* d_out, int out_size, void* d_ws, size_t ws_size,
                              hipStream_t stream) {
    const float* x = (const float*)d_in[0];
    float* ws = (float*)d_ws;
    float* gram = ws;                  // 16384
    float* colsum = ws + 16384;        // 128
    float* W = ws + 16512;             // 16384
    float* m = ws + 32896;             // 128
    float* colpart = ws + 40960;       // up to 1024*128
    float* part = ws + 172032;         // up to 1024*16384
    float* out = (float*)d_out;

    int nP = 0;
    for (int cand = 1024; cand >= 256; cand >>= 1) {
        size_t need = ((size_t)172032 + (size_t)cand * 16384) * sizeof(float);
        if (ws_size >= need) { nP = cand; break; }
    }

    if (nP > 0) {
        int cpb = 16384 / nP;   // chunks of 32 rows per block
        k_gram<1><<<nP, 256, 0, stream>>>(x, part, colpart, gram, colsum, cpb);
        k_reduce<<<65, 256, 0, stream>>>(part, colpart, gram, colsum, nP);
    } else {
        hipMemsetAsync(d_ws, 0, (16384 + 128) * sizeof(float), stream);
        k_gram<0><<<512, 256, 0, stream>>>(x, part, colpart, gram, colsum, 32);
    }
    k_chol<<<1, 256, 0, stream>>>(gram, colsum, W, m);
    k_apply<<<NROWS / 128, 256, 0, stream>>>(x, W, m, out);
}

// Round 7
// 446.067 us; speedup vs baseline: 7.2282x; 1.5074x over previous
//
#include <hip/hip_runtime.h>

#define NROWS 524288
#define NCH 128
#define GSTR 40

typedef __attribute__((ext_vector_type(8))) short bf16x8;
typedef __attribute__((ext_vector_type(4))) float f32x4;

static __device__ __forceinline__ unsigned short f2bf_rne(float f) {
    unsigned u = __float_as_uint(f);
    return (unsigned short)((u + 0x7FFFu + ((u >> 16) & 1u)) >> 16);
}

static __device__ __forceinline__ bf16x8 ldfrag(const unsigned short* base, int c, int s0) {
    int m = (c >> 3) & 12;
    return *(const bf16x8*)(base + c * GSTR + 2 * (s0 ^ m));
}

// ---------------------------------------------------------------------------
// k_gram: G2 = H^T H + H^T (2L), x = h + l (hi/lo bf16 split); k_chol
// symmetrizes sym(G2) = H^T H + H^T L + L^T H exactly.  Depth-2 register
// prefetch + double-buffered LDS, one barrier per chunk (R6-proven).
// ---------------------------------------------------------------------------
#define PACKW1(B, c, x0, x1, csacc) do {                                      \
    unsigned u0 = __float_as_uint(x0), u1 = __float_as_uint(x1);              \
    unsigned packH = (u0 >> 16) | (u1 & 0xFFFF0000u);                         \
    float l0_ = 2.0f * ((x0) - __uint_as_float(u0 & 0xFFFF0000u));            \
    float l1_ = 2.0f * ((x1) - __uint_as_float(u1 & 0xFFFF0000u));            \
    unsigned packL = (unsigned)f2bf_rne(l0_) | ((unsigned)f2bf_rne(l1_) << 16); \
    int idx_ = (c) * GSTR + 2 * (p ^ (cg & 12));                              \
    *(unsigned*)&XT[B][0][idx_] = packH;                                      \
    *(unsigned*)&XT[B][1][idx_] = packL;                                      \
    csacc += (x0) + (x1);                                                     \
} while (0)

#define LOADR(ci, r0, r1, r2, r3) do {                                        \
    const float4* s4_ = (const float4*)x + ((size_t)(ci) * 32 + 2 * p) * 32 + cg * 2; \
    r0 = s4_[0]; r1 = s4_[1]; r2 = s4_[32]; r3 = s4_[33];                     \
} while (0)

#define PACKALL(B, r0, r1, r2, r3) do {                                       \
    PACKW1(B, cg * 8 + 0, r0.x, r2.x, cs0);                                   \
    PACKW1(B, cg * 8 + 1, r0.y, r2.y, cs1);                                   \
    PACKW1(B, cg * 8 + 2, r0.z, r2.z, cs2);                                   \
    PACKW1(B, cg * 8 + 3, r0.w, r2.w, cs3);                                   \
    PACKW1(B, cg * 8 + 4, r1.x, r3.x, cs4);                                   \
    PACKW1(B, cg * 8 + 5, r1.y, r3.y, cs5);                                   \
    PACKW1(B, cg * 8 + 6, r1.z, r3.z, cs6);                                   \
    PACKW1(B, cg * 8 + 7, r1.w, r3.w, cs7);                                   \
} while (0)

#define MFMA_STEP(B) do {                                                     \
    const unsigned short* Xh = &XT[B][0][0];                                  \
    const unsigned short* Xl = &XT[B][1][0];                                  \
    bf16x8 ah0 = ldfrag(Xh, (2 * w + 0) * 16 + lc, ls);                       \
    bf16x8 ah1 = ldfrag(Xh, (2 * w + 1) * 16 + lc, ls);                       \
    _Pragma("unroll")                                                         \
    for (int tj = 0; tj < 8; ++tj) {                                          \
        bf16x8 bh = ldfrag(Xh, tj * 16 + lc, ls);                             \
        bf16x8 bl = ldfrag(Xl, tj * 16 + lc, ls);                             \
        acc[0][tj] = __builtin_amdgcn_mfma_f32_16x16x32_bf16(ah0, bh, acc[0][tj], 0, 0, 0); \
        acc[0][tj] = __builtin_amdgcn_mfma_f32_16x16x32_bf16(ah0, bl, acc[0][tj], 0, 0, 0); \
        acc[1][tj] = __builtin_amdgcn_mfma_f32_16x16x32_bf16(ah1, bh, acc[1][tj], 0, 0, 0); \
        acc[1][tj] = __builtin_amdgcn_mfma_f32_16x16x32_bf16(ah1, bl, acc[1][tj], 0, 0, 0); \
    }                                                                         \
} while (0)

template <int STORE>
__global__ __launch_bounds__(256, 3) void k_gram(const float* __restrict__ x,
                                                 float* __restrict__ part,
                                                 float* __restrict__ colpart,
                                                 float* __restrict__ gram,
                                                 float* __restrict__ colsum,
                                                 int cpb) {
    __shared__ __align__(16) unsigned short XT[2][2][128 * GSTR];  // [buf][hi/lo]
    const int tid = threadIdx.x;
    const int w = tid >> 6;
    const int l = tid & 63;
    const int lc = l & 15;
    const int ls = (l >> 4) * 4;
    const int p = tid >> 4;          // row-pair (rows 2p,2p+1 of chunk)
    const int cg = tid & 15;         // channel-group (8 ch), lane-minor

    f32x4 acc[2][8];
#pragma unroll
    for (int a = 0; a < 2; ++a)
#pragma unroll
        for (int t = 0; t < 8; ++t) acc[a][t] = (f32x4){0.f, 0.f, 0.f, 0.f};
    float cs0 = 0.f, cs1 = 0.f, cs2 = 0.f, cs3 = 0.f;
    float cs4 = 0.f, cs5 = 0.f, cs6 = 0.f, cs7 = 0.f;

    const int c0 = blockIdx.x * cpb;
    float4 a0, a1, a2, a3, b0, b1, b2, b3;

    LOADR(c0 + 0, a0, a1, a2, a3);
    LOADR(c0 + 1, b0, b1, b2, b3);
    PACKALL(0, a0, a1, a2, a3);
    __syncthreads();

#pragma unroll 1
    for (int t = 0; t < cpb; t += 2) {
        MFMA_STEP(0);                         // chunk t
        PACKALL(1, b0, b1, b2, b3);           // chunk t+1 -> LDS[1]
        if (t + 2 < cpb) LOADR(c0 + t + 2, a0, a1, a2, a3);
        __syncthreads();
        MFMA_STEP(1);                         // chunk t+1
        if (t + 2 < cpb) {
            PACKALL(0, a0, a1, a2, a3);       // chunk t+2 -> LDS[0]
            if (t + 3 < cpb) LOADR(c0 + t + 3, b0, b1, b2, b3);
            __syncthreads();
        }
    }

    // intra-block colsum reduction (reuse XT as float LDS)
    __syncthreads();
    float* cls = (float*)&XT[0][0][0];        // 128 ch x 16 pairs
    cls[(cg * 8 + 0) * 16 + p] = cs0;
    cls[(cg * 8 + 1) * 16 + p] = cs1;
    cls[(cg * 8 + 2) * 16 + p] = cs2;
    cls[(cg * 8 + 3) * 16 + p] = cs3;
    cls[(cg * 8 + 4) * 16 + p] = cs4;
    cls[(cg * 8 + 5) * 16 + p] = cs5;
    cls[(cg * 8 + 6) * 16 + p] = cs6;
    cls[(cg * 8 + 7) * 16 + p] = cs7;
    __syncthreads();
    float csr = 0.f;
    if (tid < 128) {
#pragma unroll
        for (int pp = 0; pp < 16; ++pp) csr += cls[tid * 16 + pp];
    }

    if (STORE) {
        float* pb = part + (size_t)blockIdx.x * 16384;
#pragma unroll
        for (int a = 0; a < 2; ++a)
#pragma unroll
            for (int tj = 0; tj < 8; ++tj)
#pragma unroll
                for (int q = 0; q < 4; ++q) {
                    int row = (2 * w + a) * 16 + (l >> 4) * 4 + q;
                    int col = tj * 16 + lc;
                    pb[row * NCH + col] = acc[a][tj][q];
                }
        if (tid < 128) colpart[blockIdx.x * 128 + tid] = csr;
    } else {
#pragma unroll
        for (int a = 0; a < 2; ++a)
#pragma unroll
            for (int tj = 0; tj < 8; ++tj)
#pragma unroll
                for (int q = 0; q < 4; ++q) {
                    int row = (2 * w + a) * 16 + (l >> 4) * 4 + q;
                    int col = tj * 16 + lc;
                    atomicAdd(&gram[row * NCH + col], acc[a][tj][q]);
                }
        if (tid < 128) atomicAdd(&colsum[tid], csr);
    }
}

// ---------------------------------------------------------------------------
// Two-stage tree reduction of per-block partials.
// Stage 1: NG groups of 32 partial-blocks; 16 e-slices of 1024 elems.
//   grid = 16*NG + NG blocks; each thread sums 32 float4 (unrolled -> MLP).
// Stage 2: 17 blocks fold NG group-partials into gram / colsum.
// ---------------------------------------------------------------------------
__global__ __launch_bounds__(256) void k_reduce1(const float* __restrict__ part,
                                                 const float* __restrict__ colpart,
                                                 float* __restrict__ part2,
                                                 float* __restrict__ col2,
                                                 int NG) {
    const int b = blockIdx.x;
    if (b < 16 * NG) {
        const int g = b >> 4;
        const int sl = b & 15;
        const int e4 = sl * 1024 + threadIdx.x * 4;
        const float* p0 = part + (size_t)g * 32 * 16384 + e4;
        float4 s = {0.f, 0.f, 0.f, 0.f};
#pragma unroll
        for (int k = 0; k < 32; ++k) {
            float4 v = *(const float4*)(p0 + (size_t)k * 16384);
            s.x += v.x; s.y += v.y; s.z += v.z; s.w += v.w;
        }
        *(float4*)(part2 + (size_t)g * 16384 + e4) = s;
    } else {
        const int g = b - 16 * NG;
        if (threadIdx.x < 128) {
            const float* c0 = colpart + g * 32 * 128 + threadIdx.x;
            float s = 0.f;
#pragma unroll
            for (int k = 0; k < 32; ++k) s += c0[k * 128];
            col2[g * 128 + threadIdx.x] = s;
        }
    }
}

__global__ __launch_bounds__(256) void k_reduce2(const float* __restrict__ part2,
                                                 const float* __restrict__ col2,
                                                 float* __restrict__ gram,
                                                 float* __restrict__ colsum,
                                                 int NG) {
    const int b = blockIdx.x;
    if (b < 16) {
        const int e4 = b * 1024 + threadIdx.x * 4;
        float4 s = {0.f, 0.f, 0.f, 0.f};
#pragma unroll 8
        for (int g = 0; g < NG; ++g) {
            float4 v = *(const float4*)(part2 + (size_t)g * 16384 + e4);
            s.x += v.x; s.y += v.y; s.z += v.z; s.w += v.w;
        }
        *(float4*)(gram + e4) = s;
    } else if (threadIdx.x < 128) {
        float s = 0.f;
#pragma unroll 8
        for (int g = 0; g < NG; ++g) s += col2[g * 128 + threadIdx.x];
        colsum[threadIdx.x] = s;
    }
}

// ---------------------------------------------------------------------------
// k_chol: symmetrize G2, parallel Cholesky + triangular inverse (unchanged).
// ---------------------------------------------------------------------------
__global__ __launch_bounds__(256) void k_chol(const float* __restrict__ gram,
                                              const float* __restrict__ colsum,
                                              float* __restrict__ Wout,
                                              float* __restrict__ mout) {
    __shared__ float A[128][129];
    __shared__ float B[128][129];
    __shared__ float m[128];
    __shared__ float dsq[128];
    __shared__ float rd2[128];
    const int tid = threadIdx.x;

    if (tid < 128) {
        m[tid] = colsum[tid] * (1.0f / (float)NROWS);
        mout[tid] = m[tid];
    }
    __syncthreads();
    for (int idx = tid; idx < 128 * 128; idx += 256) {
        int i = idx >> 7, j = idx & 127;
        float g = 0.5f * (gram[i * NCH + j] + gram[j * NCH + i]);   // sym(G2)
        A[i][j] = (g - (float)NROWS * m[i] * m[j]) * (1.0f / (float)(NROWS - 1));
        B[i][j] = (i == j) ? 1.0f : 0.0f;
    }

    const int q = tid >> 1;
    const int h = tid & 1;
    for (int k = 0; k < 127; ++k) {
        __syncthreads();
        float rd = 1.0f / A[k][k];
        int j = k + 1 + q;
        if (j < 128) {
            float fj = A[j][k] * rd;
            for (int i = k + 1 + h; i < 128; i += 2)
                A[j][i] -= fj * A[k][i];
        }
    }
    __syncthreads();
    if (tid < 128) {
        float d = A[tid][tid];
        dsq[tid] = 1.0f / sqrtf(d);
        rd2[tid] = 1.0f / d;
    }

    for (int r = 0; r < 127; ++r) {
        __syncthreads();
        int j = r + 1 + q;
        if (j < 128) {
            float f = A[j][r] * rd2[r];
            for (int c = h; c <= r; c += 2)
                B[j][c] -= f * B[r][c];
        }
    }
    __syncthreads();

    for (int idx = tid; idx < 128 * 128; idx += 256) {
        int j = idx >> 7, c = idx & 127;
        float vv = (c < j) ? B[j][c] * dsq[j] : ((c == j) ? dsq[j] : 0.0f);
        Wout[idx] = vv;
    }
}

// ---------------------------------------------------------------------------
// k_apply: out = xn + bf16(xn) @ R^T, R = W - I (unchanged, healthy).
// ---------------------------------------------------------------------------
__global__ __launch_bounds__(256, 3) void k_apply(const float* __restrict__ x,
                                                  const float* __restrict__ Wg,
                                                  const float* __restrict__ mg,
                                                  float* __restrict__ out) {
    __shared__ __align__(16) unsigned char XS[128 * 128];
    __shared__ float msh[128];
    const int tid = threadIdx.x;
    const int w = tid >> 6, l = tid & 63;
    const int lc = l & 15, la = l >> 4;

    if (tid < 32) *(float4*)&msh[tid * 4] = *(const float4*)&mg[tid * 4];
    __syncthreads();

    bf16x8 rfrag[2][4];
#pragma unroll
    for (int tjl = 0; tjl < 2; ++tjl) {
        int j = (w * 2 + tjl) * 16 + lc;
#pragma unroll
        for (int ks = 0; ks < 4; ++ks) {
            int i0 = ks * 32 + la * 8;
            float4 wa = *(const float4*)&Wg[j * 128 + i0];
            float4 wb = *(const float4*)&Wg[j * 128 + i0 + 4];
            rfrag[tjl][ks][0] = f2bf_rne(wa.x - ((j == i0 + 0) ? 1.0f : 0.0f));
            rfrag[tjl][ks][1] = f2bf_rne(wa.y - ((j == i0 + 1) ? 1.0f : 0.0f));
            rfrag[tjl][ks][2] = f2bf_rne(wa.z - ((j == i0 + 2) ? 1.0f : 0.0f));
            rfrag[tjl][ks][3] = f2bf_rne(wa.w - ((j == i0 + 3) ? 1.0f : 0.0f));
            rfrag[tjl][ks][4] = f2bf_rne(wb.x - ((j == i0 + 4) ? 1.0f : 0.0f));
            rfrag[tjl][ks][5] = f2bf_rne(wb.y - ((j == i0 + 5) ? 1.0f : 0.0f));
            rfrag[tjl][ks][6] = f2bf_rne(wb.z - ((j == i0 + 6) ? 1.0f : 0.0f));
            rfrag[tjl][ks][7] = f2bf_rne(wb.w - ((j == i0 + 7) ? 1.0f : 0.0f));
        }
    }

    f32x4 acc[8][2];
#pragma unroll
    for (int ti = 0; ti < 8; ++ti)
#pragma unroll
        for (int tjl = 0; tjl < 2; ++tjl) acc[ti][tjl] = (f32x4){0.f, 0.f, 0.f, 0.f};

    const size_t rowbase = (size_t)blockIdx.x * 128;

#pragma unroll
    for (int c = 0; c < 2; ++c) {
        const int kb = c * 64;
#pragma unroll
        for (int rep = 0; rep < 8; ++rep) {
            int f = tid + 256 * rep;
            int r = f >> 4, i4 = f & 15;
            float4 vx = *(const float4*)&x[(rowbase + r) * 128 + kb + i4 * 4];
            float4 mv = *(const float4*)&msh[kb + i4 * 4];
            unsigned b0 = f2bf_rne(vx.x - mv.x);
            unsigned b1 = f2bf_rne(vx.y - mv.y);
            unsigned b2 = f2bf_rne(vx.z - mv.z);
            unsigned b3 = f2bf_rne(vx.w - mv.w);
            unsigned off = r * 128 + ((((i4 >> 1) ^ (r & 7))) << 4) + (i4 & 1) * 8;
            *(uint2*)(XS + off) = make_uint2(b0 | (b1 << 16), b2 | (b3 << 16));
        }
        __syncthreads();
#pragma unroll
        for (int ksl = 0; ksl < 2; ++ksl) {
#pragma unroll
            for (int ti = 0; ti < 8; ++ti) {
                int r = ti * 16 + lc;
                int g = ksl * 4 + la;
                bf16x8 af = *(const bf16x8*)(XS + r * 128 + ((g ^ (r & 7)) << 4));
                acc[ti][0] = __builtin_amdgcn_mfma_f32_16x16x32_bf16(af, rfrag[0][c * 2 + ksl], acc[ti][0], 0, 0, 0);
                acc[ti][1] = __builtin_amdgcn_mfma_f32_16x16x32_bf16(af, rfrag[1][c * 2 + ksl], acc[ti][1], 0, 0, 0);
            }
        }
        __syncthreads();
    }

#pragma unroll
    for (int ti = 0; ti < 8; ++ti)
#pragma unroll
        for (int tjl = 0; tjl < 2; ++tjl)
#pragma unroll
            for (int q = 0; q < 4; ++q) {
                int rloc = ti * 16 + la * 4 + q;
                int cglob = (w * 2 + tjl) * 16 + lc;
                size_t a = (rowbase + rloc) * 128 + cglob;
                out[a] = (x[a] - msh[cglob]) + acc[ti][tjl][q];
            }
}

extern "C" void kernel_launch(void* const* d_in, const int* in_sizes, int n_in,
                              void* d_out, int out_size, void* d_ws, size_t ws_size,
                              hipStream_t stream) {
    const float* x = (const float*)d_in[0];
    float* ws = (float*)d_ws;
    float* gram = ws;                  // 16384
    float* colsum = ws + 16384;        // 128
    float* W = ws + 16512;             // 16384
    float* m = ws + 32896;             // 128
    float* colpart = ws + 40960;       // up to 1024*128
    float* part = ws + 172032;         // nP*16384
    float* out = (float*)d_out;

    int nP = 0;
    for (int cand = 1024; cand >= 256; cand >>= 1) {
        int ng = cand / 32;
        size_t need = ((size_t)172032 + (size_t)cand * 16384 +
                       (size_t)ng * 16384 + (size_t)ng * 128) * sizeof(float);
        if (ws_size >= need) { nP = cand; break; }
    }

    if (nP > 0) {
        const int NG = nP / 32;
        float* part2 = part + (size_t)nP * 16384;
        float* col2 = part2 + (size_t)NG * 16384;
        int cpb = 16384 / nP;
        k_gram<1><<<nP, 256, 0, stream>>>(x, part, colpart, gram, colsum, cpb);
        k_reduce1<<<16 * NG + NG, 256, 0, stream>>>(part, colpart, part2, col2, NG);
        k_reduce2<<<17, 256, 0, stream>>>(part2, col2, gram, colsum, NG);
    } else {
        hipMemsetAsync(d_ws, 0, (16384 + 128) * sizeof(float), stream);
        k_gram<0><<<512, 256, 0, stream>>>(x, part, colpart, gram, colsum, 32);
    }
    k_chol<<<1, 256, 0, stream>>>(gram, colsum, W, m);
    k_apply<<<NROWS / 128, 256, 0, stream>>>(x, W, m, out);
}

// Round 8
// 345.495 us; speedup vs baseline: 9.3322x; 1.2911x over previous
//
#include <hip/hip_runtime.h>

#define NROWS 524288
#define NCH 128
#define GSTR 40

typedef __attribute__((ext_vector_type(8))) short bf16x8;
typedef __attribute__((ext_vector_type(4))) float f32x4;

static __device__ __forceinline__ unsigned short f2bf_rne(float f) {
    unsigned u = __float_as_uint(f);
    return (unsigned short)((u + 0x7FFFu + ((u >> 16) & 1u)) >> 16);
}

static __device__ __forceinline__ bf16x8 ldfrag(const unsigned short* base, int c, int s0) {
    int m = (c >> 3) & 12;
    return *(const bf16x8*)(base + c * GSTR + 2 * (s0 ^ m));
}

// ---------------------------------------------------------------------------
// k_gram: G2 = H^T H + H^T (2L), x = h + l (hi/lo bf16 split); k_chol
// symmetrizes sym(G2) = H^T H + H^T L + L^T H exactly.  Depth-2 register
// prefetch + double-buffered LDS, one barrier per chunk (R6-proven).
// ---------------------------------------------------------------------------
#define PACKW1(B, c, x0, x1, csacc) do {                                      \
    unsigned u0 = __float_as_uint(x0), u1 = __float_as_uint(x1);              \
    unsigned packH = (u0 >> 16) | (u1 & 0xFFFF0000u);                         \
    float l0_ = 2.0f * ((x0) - __uint_as_float(u0 & 0xFFFF0000u));            \
    float l1_ = 2.0f * ((x1) - __uint_as_float(u1 & 0xFFFF0000u));            \
    unsigned packL = (unsigned)f2bf_rne(l0_) | ((unsigned)f2bf_rne(l1_) << 16); \
    int idx_ = (c) * GSTR + 2 * (p ^ (cg & 12));                              \
    *(unsigned*)&XT[B][0][idx_] = packH;                                      \
    *(unsigned*)&XT[B][1][idx_] = packL;                                      \
    csacc += (x0) + (x1);                                                     \
} while (0)

#define LOADR(ci, r0, r1, r2, r3) do {                                        \
    const float4* s4_ = (const float4*)x + ((size_t)(ci) * 32 + 2 * p) * 32 + cg * 2; \
    r0 = s4_[0]; r1 = s4_[1]; r2 = s4_[32]; r3 = s4_[33];                     \
} while (0)

#define PACKALL(B, r0, r1, r2, r3) do {                                       \
    PACKW1(B, cg * 8 + 0, r0.x, r2.x, cs0);                                   \
    PACKW1(B, cg * 8 + 1, r0.y, r2.y, cs1);                                   \
    PACKW1(B, cg * 8 + 2, r0.z, r2.z, cs2);                                   \
    PACKW1(B, cg * 8 + 3, r0.w, r2.w, cs3);                                   \
    PACKW1(B, cg * 8 + 4, r1.x, r3.x, cs4);                                   \
    PACKW1(B, cg * 8 + 5, r1.y, r3.y, cs5);                                   \
    PACKW1(B, cg * 8 + 6, r1.z, r3.z, cs6);                                   \
    PACKW1(B, cg * 8 + 7, r1.w, r3.w, cs7);                                   \
} while (0)

#define MFMA_STEP(B) do {                                                     \
    const unsigned short* Xh = &XT[B][0][0];                                  \
    const unsigned short* Xl = &XT[B][1][0];                                  \
    bf16x8 ah0 = ldfrag(Xh, (2 * w + 0) * 16 + lc, ls);                       \
    bf16x8 ah1 = ldfrag(Xh, (2 * w + 1) * 16 + lc, ls);                       \
    _Pragma("unroll")                                                         \
    for (int tj = 0; tj < 8; ++tj) {                                          \
        bf16x8 bh = ldfrag(Xh, tj * 16 + lc, ls);                             \
        bf16x8 bl = ldfrag(Xl, tj * 16 + lc, ls);                             \
        acc[0][tj] = __builtin_amdgcn_mfma_f32_16x16x32_bf16(ah0, bh, acc[0][tj], 0, 0, 0); \
        acc[0][tj] = __builtin_amdgcn_mfma_f32_16x16x32_bf16(ah0, bl, acc[0][tj], 0, 0, 0); \
        acc[1][tj] = __builtin_amdgcn_mfma_f32_16x16x32_bf16(ah1, bh, acc[1][tj], 0, 0, 0); \
        acc[1][tj] = __builtin_amdgcn_mfma_f32_16x16x32_bf16(ah1, bl, acc[1][tj], 0, 0, 0); \
    }                                                                         \
} while (0)

template <int STORE>
__global__ __launch_bounds__(256, 3) void k_gram(const float* __restrict__ x,
                                                 float* __restrict__ part,
                                                 float* __restrict__ colpart,
                                                 float* __restrict__ gram,
                                                 float* __restrict__ colsum,
                                                 int cpb) {
    __shared__ __align__(16) unsigned short XT[2][2][128 * GSTR];  // [buf][hi/lo]
    const int tid = threadIdx.x;
    const int w = tid >> 6;
    const int l = tid & 63;
    const int lc = l & 15;
    const int ls = (l >> 4) * 4;
    const int p = tid >> 4;          // row-pair (rows 2p,2p+1 of chunk)
    const int cg = tid & 15;         // channel-group (8 ch), lane-minor

    f32x4 acc[2][8];
#pragma unroll
    for (int a = 0; a < 2; ++a)
#pragma unroll
        for (int t = 0; t < 8; ++t) acc[a][t] = (f32x4){0.f, 0.f, 0.f, 0.f};
    float cs0 = 0.f, cs1 = 0.f, cs2 = 0.f, cs3 = 0.f;
    float cs4 = 0.f, cs5 = 0.f, cs6 = 0.f, cs7 = 0.f;

    const int c0 = blockIdx.x * cpb;
    float4 a0, a1, a2, a3, b0, b1, b2, b3;

    LOADR(c0 + 0, a0, a1, a2, a3);
    LOADR(c0 + 1, b0, b1, b2, b3);
    PACKALL(0, a0, a1, a2, a3);
    __syncthreads();

#pragma unroll 1
    for (int t = 0; t < cpb; t += 2) {
        MFMA_STEP(0);                         // chunk t
        PACKALL(1, b0, b1, b2, b3);           // chunk t+1 -> LDS[1]
        if (t + 2 < cpb) LOADR(c0 + t + 2, a0, a1, a2, a3);
        __syncthreads();
        MFMA_STEP(1);                         // chunk t+1
        if (t + 2 < cpb) {
            PACKALL(0, a0, a1, a2, a3);       // chunk t+2 -> LDS[0]
            if (t + 3 < cpb) LOADR(c0 + t + 3, b0, b1, b2, b3);
            __syncthreads();
        }
    }

    // intra-block colsum reduction (reuse XT as float LDS)
    __syncthreads();
    float* cls = (float*)&XT[0][0][0];        // 128 ch x 16 pairs
    cls[(cg * 8 + 0) * 16 + p] = cs0;
    cls[(cg * 8 + 1) * 16 + p] = cs1;
    cls[(cg * 8 + 2) * 16 + p] = cs2;
    cls[(cg * 8 + 3) * 16 + p] = cs3;
    cls[(cg * 8 + 4) * 16 + p] = cs4;
    cls[(cg * 8 + 5) * 16 + p] = cs5;
    cls[(cg * 8 + 6) * 16 + p] = cs6;
    cls[(cg * 8 + 7) * 16 + p] = cs7;
    __syncthreads();
    float csr = 0.f;
    if (tid < 128) {
#pragma unroll
        for (int pp = 0; pp < 16; ++pp) csr += cls[tid * 16 + pp];
    }

    if (STORE) {
        float* pb = part + (size_t)blockIdx.x * 16384;
#pragma unroll
        for (int a = 0; a < 2; ++a)
#pragma unroll
            for (int tj = 0; tj < 8; ++tj)
#pragma unroll
                for (int q = 0; q < 4; ++q) {
                    int row = (2 * w + a) * 16 + (l >> 4) * 4 + q;
                    int col = tj * 16 + lc;
                    pb[row * NCH + col] = acc[a][tj][q];
                }
        if (tid < 128) colpart[blockIdx.x * 128 + tid] = csr;
    } else {
#pragma unroll
        for (int a = 0; a < 2; ++a)
#pragma unroll
            for (int tj = 0; tj < 8; ++tj)
#pragma unroll
                for (int q = 0; q < 4; ++q) {
                    int row = (2 * w + a) * 16 + (l >> 4) * 4 + q;
                    int col = tj * 16 + lc;
                    atomicAdd(&gram[row * NCH + col], acc[a][tj][q]);
                }
        if (tid < 128) atomicAdd(&colsum[tid], csr);
    }
}

// ---------------------------------------------------------------------------
// Two-stage tree reduction of per-block partials (R7-proven).
// ---------------------------------------------------------------------------
__global__ __launch_bounds__(256) void k_reduce1(const float* __restrict__ part,
                                                 const float* __restrict__ colpart,
                                                 float* __restrict__ part2,
                                                 float* __restrict__ col2,
                                                 int NG) {
    const int b = blockIdx.x;
    if (b < 16 * NG) {
        const int g = b >> 4;
        const int sl = b & 15;
        const int e4 = sl * 1024 + threadIdx.x * 4;
        const float* p0 = part + (size_t)g * 32 * 16384 + e4;
        float4 s = {0.f, 0.f, 0.f, 0.f};
#pragma unroll
        for (int k = 0; k < 32; ++k) {
            float4 v = *(const float4*)(p0 + (size_t)k * 16384);
            s.x += v.x; s.y += v.y; s.z += v.z; s.w += v.w;
        }
        *(float4*)(part2 + (size_t)g * 16384 + e4) = s;
    } else {
        const int g = b - 16 * NG;
        if (threadIdx.x < 128) {
            const float* c0 = colpart + g * 32 * 128 + threadIdx.x;
            float s = 0.f;
#pragma unroll
            for (int k = 0; k < 32; ++k) s += c0[k * 128];
            col2[g * 128 + threadIdx.x] = s;
        }
    }
}

__global__ __launch_bounds__(256) void k_reduce2(const float* __restrict__ part2,
                                                 const float* __restrict__ col2,
                                                 float* __restrict__ gram,
                                                 float* __restrict__ colsum,
                                                 int NG) {
    const int b = blockIdx.x;
    if (b < 16) {
        const int e4 = b * 1024 + threadIdx.x * 4;
        float4 s = {0.f, 0.f, 0.f, 0.f};
#pragma unroll 8
        for (int g = 0; g < NG; ++g) {
            float4 v = *(const float4*)(part2 + (size_t)g * 16384 + e4);
            s.x += v.x; s.y += v.y; s.z += v.z; s.w += v.w;
        }
        *(float4*)(gram + e4) = s;
    } else if (threadIdx.x < 128) {
        float s = 0.f;
#pragma unroll 8
        for (int g = 0; g < NG; ++g) s += col2[g * 128 + threadIdx.x];
        colsum[threadIdx.x] = s;
    }
}

// ---------------------------------------------------------------------------
// k_chol: fused Gauss-Jordan, 1024 threads, float4 LDS.
// Combined C[j] = [ B(128) | A(128) ], B = I -> M (unit-lower multipliers),
// A = cov.  Step k: fj = A[j][k]/D_k; row j -= fj * row k over B cols 0..k
// and A cols k+1..127 (4-aligned; masked pivot makes edge writes no-ops).
// After 127 steps: L^{-1}[j][c] = B[j][c]/sqrt(D_j), diag = 1/sqrt(D_j).
// Half the barriers of the two-phase version, 4x threads, float4 ops.
// ---------------------------------------------------------------------------
__global__ __launch_bounds__(1024) void k_chol(const float* __restrict__ gram,
                                               const float* __restrict__ colsum,
                                               float* __restrict__ Wout,
                                               float* __restrict__ mout) {
    __shared__ float C[128][264];   // [0..127]=B, [128..255]=A, 8 pad
    __shared__ float m[128];
    __shared__ float dsq[128];
    const int tid = threadIdx.x;
    const int rs = tid >> 5;        // rowslot 0..31
    const int cs = tid & 31;        // colslot 0..31

    if (tid < 128) {
        m[tid] = colsum[tid] * (1.0f / (float)NROWS);
        mout[tid] = m[tid];
    }
    __syncthreads();
    for (int idx = tid; idx < 128 * 128; idx += 1024) {
        int i = idx >> 7, j = idx & 127;
        float g = 0.5f * (gram[i * NCH + j] + gram[j * NCH + i]);   // sym(G2)
        C[i][128 + j] = (g - (float)NROWS * m[i] * m[j]) * (1.0f / (float)(NROWS - 1));
        C[i][j] = (i == j) ? 1.0f : 0.0f;
    }
    __syncthreads();

#pragma unroll 1
    for (int k = 0; k < 127; ++k) {
        float piv = C[k][128 + k];
        float rd = 1.0f / piv;
        if (tid == 0) dsq[k] = 1.0f / sqrtf(piv);

        const int gs = (k + 1) >> 2;          // first A-side float4 group
        const int rmask = (k + 1) & 3;        // comps of group gs with col <= k
        const bool doB = (cs <= (k >> 2));
        const int gA = gs + cs;
        const bool doA = (gA < 32);

        float4 pb, pa;
        if (doB) pb = *(const float4*)&C[k][cs * 4];
        if (doA) {
            pa = *(const float4*)&C[k][128 + gA * 4];
            if (cs == 0) {                    // mask cols <= k (writes become no-ops)
                if (rmask > 0) pa.x = 0.f;
                if (rmask > 1) pa.y = 0.f;
                if (rmask > 2) pa.z = 0.f;
            }
        }

        for (int j = k + 1 + rs; j < 128; j += 32) {
            float fj = C[j][128 + k] * rd;
            if (doB) {
                float4 v = *(const float4*)&C[j][cs * 4];
                v.x -= fj * pb.x; v.y -= fj * pb.y; v.z -= fj * pb.z; v.w -= fj * pb.w;
                *(float4*)&C[j][cs * 4] = v;
            }
            if (doA) {
                float4 v = *(const float4*)&C[j][128 + gA * 4];
                v.x -= fj * pa.x; v.y -= fj * pa.y; v.z -= fj * pa.z; v.w -= fj * pa.w;
                *(float4*)&C[j][128 + gA * 4] = v;
            }
        }
        __syncthreads();
    }
    if (tid == 0) dsq[127] = 1.0f / sqrtf(C[127][128 + 127]);
    __syncthreads();

    for (int idx = tid; idx < 128 * 128; idx += 1024) {
        int j = idx >> 7, c = idx & 127;
        float vv = (c < j) ? C[j][c] * dsq[j] : ((c == j) ? dsq[j] : 0.0f);
        Wout[idx] = vv;
    }
}

// ---------------------------------------------------------------------------
// k_apply: out = xn + bf16(xn) @ R^T, R = W - I (unchanged, healthy).
// ---------------------------------------------------------------------------
__global__ __launch_bounds__(256, 3) void k_apply(const float* __restrict__ x,
                                                  const float* __restrict__ Wg,
                                                  const float* __restrict__ mg,
                                                  float* __restrict__ out) {
    __shared__ __align__(16) unsigned char XS[128 * 128];
    __shared__ float msh[128];
    const int tid = threadIdx.x;
    const int w = tid >> 6, l = tid & 63;
    const int lc = l & 15, la = l >> 4;

    if (tid < 32) *(float4*)&msh[tid * 4] = *(const float4*)&mg[tid * 4];
    __syncthreads();

    bf16x8 rfrag[2][4];
#pragma unroll
    for (int tjl = 0; tjl < 2; ++tjl) {
        int j = (w * 2 + tjl) * 16 + lc;
#pragma unroll
        for (int ks = 0; ks < 4; ++ks) {
            int i0 = ks * 32 + la * 8;
            float4 wa = *(const float4*)&Wg[j * 128 + i0];
            float4 wb = *(const float4*)&Wg[j * 128 + i0 + 4];
            rfrag[tjl][ks][0] = f2bf_rne(wa.x - ((j == i0 + 0) ? 1.0f : 0.0f));
            rfrag[tjl][ks][1] = f2bf_rne(wa.y - ((j == i0 + 1) ? 1.0f : 0.0f));
            rfrag[tjl][ks][2] = f2bf_rne(wa.z - ((j == i0 + 2) ? 1.0f : 0.0f));
            rfrag[tjl][ks][3] = f2bf_rne(wa.w - ((j == i0 + 3) ? 1.0f : 0.0f));
            rfrag[tjl][ks][4] = f2bf_rne(wb.x - ((j == i0 + 4) ? 1.0f : 0.0f));
            rfrag[tjl][ks][5] = f2bf_rne(wb.y - ((j == i0 + 5) ? 1.0f : 0.0f));
            rfrag[tjl][ks][6] = f2bf_rne(wb.z - ((j == i0 + 6) ? 1.0f : 0.0f));
            rfrag[tjl][ks][7] = f2bf_rne(wb.w - ((j == i0 + 7) ? 1.0f : 0.0f));
        }
    }

    f32x4 acc[8][2];
#pragma unroll
    for (int ti = 0; ti < 8; ++ti)
#pragma unroll
        for (int tjl = 0; tjl < 2; ++tjl) acc[ti][tjl] = (f32x4){0.f, 0.f, 0.f, 0.f};

    const size_t rowbase = (size_t)blockIdx.x * 128;

#pragma unroll
    for (int c = 0; c < 2; ++c) {
        const int kb = c * 64;
#pragma unroll
        for (int rep = 0; rep < 8; ++rep) {
            int f = tid + 256 * rep;
            int r = f >> 4, i4 = f & 15;
            float4 vx = *(const float4*)&x[(rowbase + r) * 128 + kb + i4 * 4];
            float4 mv = *(const float4*)&msh[kb + i4 * 4];
            unsigned b0 = f2bf_rne(vx.x - mv.x);
            unsigned b1 = f2bf_rne(vx.y - mv.y);
            unsigned b2 = f2bf_rne(vx.z - mv.z);
            unsigned b3 = f2bf_rne(vx.w - mv.w);
            unsigned off = r * 128 + ((((i4 >> 1) ^ (r & 7))) << 4) + (i4 & 1) * 8;
            *(uint2*)(XS + off) = make_uint2(b0 | (b1 << 16), b2 | (b3 << 16));
        }
        __syncthreads();
#pragma unroll
        for (int ksl = 0; ksl < 2; ++ksl) {
#pragma unroll
            for (int ti = 0; ti < 8; ++ti) {
                int r = ti * 16 + lc;
                int g = ksl * 4 + la;
                bf16x8 af = *(const bf16x8*)(XS + r * 128 + ((g ^ (r & 7)) << 4));
                acc[ti][0] = __builtin_amdgcn_mfma_f32_16x16x32_bf16(af, rfrag[0][c * 2 + ksl], acc[ti][0], 0, 0, 0);
                acc[ti][1] = __builtin_amdgcn_mfma_f32_16x16x32_bf16(af, rfrag[1][c * 2 + ksl], acc[ti][1], 0, 0, 0);
            }
        }
        __syncthreads();
    }

#pragma unroll
    for (int ti = 0; ti < 8; ++ti)
#pragma unroll
        for (int tjl = 0; tjl < 2; ++tjl)
#pragma unroll
            for (int q = 0; q < 4; ++q) {
                int rloc = ti * 16 + la * 4 + q;
                int cglob = (w * 2 + tjl) * 16 + lc;
                size_t a = (rowbase + rloc) * 128 + cglob;
                out[a] = (x[a] - msh[cglob]) + acc[ti][tjl][q];
            }
}

extern "C" void kernel_launch(void* const* d_in, const int* in_sizes, int n_in,
                              void* d_out, int out_size, void* d_ws, size_t ws_size,
                              hipStream_t stream) {
    const float* x = (const float*)d_in[0];
    float* ws = (float*)d_ws;
    float* gram = ws;                  // 16384
    float* colsum = ws + 16384;        // 128
    float* W = ws + 16512;             // 16384
    float* m = ws + 32896;             // 128
    float* colpart = ws + 40960;       // up to 1024*128
    float* part = ws + 172032;         // nP*16384
    float* out = (float*)d_out;

    int nP = 0;
    for (int cand = 1024; cand >= 256; cand >>= 1) {
        int ng = cand / 32;
        size_t need = ((size_t)172032 + (size_t)cand * 16384 +
                       (size_t)ng * 16384 + (size_t)ng * 128) * sizeof(float);
        if (ws_size >= need) { nP = cand; break; }
    }

    if (nP > 0) {
        const int NG = nP / 32;
        float* part2 = part + (size_t)nP * 16384;
        float* col2 = part2 + (size_t)NG * 16384;
        int cpb = 16384 / nP;
        k_gram<1><<<nP, 256, 0, stream>>>(x, part, colpart, gram, colsum, cpb);
        k_reduce1<<<16 * NG + NG, 256, 0, stream>>>(part, colpart, part2, col2, NG);
        k_reduce2<<<17, 256, 0, stream>>>(part2, col2, gram, colsum, NG);
    } else {
        hipMemsetAsync(d_ws, 0, (16384 + 128) * sizeof(float), stream);
        k_gram<0><<<512, 256, 0, stream>>>(x, part, colpart, gram, colsum, 32);
    }
    k_chol<<<1, 1024, 0, stream>>>(gram, colsum, W, m);
    k_apply<<<NROWS / 128, 256, 0, stream>>>(x, W, m, out);
}

// Round 9
// 304.401 us; speedup vs baseline: 10.5921x; 1.1350x over previous
//
#include <hip/hip_runtime.h>

#define NROWS 524288
#define NCH 128
#define GSTR 40

typedef __attribute__((ext_vector_type(8))) short bf16x8;
typedef __attribute__((ext_vector_type(4))) float f32x4;

static __device__ __forceinline__ unsigned short f2bf_rne(float f) {
    unsigned u = __float_as_uint(f);
    return (unsigned short)((u + 0x7FFFu + ((u >> 16) & 1u)) >> 16);
}

static __device__ __forceinline__ bf16x8 ldfrag(const unsigned short* base, int c, int s0) {
    int m = (c >> 3) & 12;
    return *(const bf16x8*)(base + c * GSTR + 2 * (s0 ^ m));
}

// ---------------------------------------------------------------------------
// k_gram: G2 = H^T H + H^T (2L), x = h + l (hi/lo bf16 split); k_chol
// symmetrizes sym(G2) = H^T H + H^T L + L^T H exactly.  Depth-2 register
// prefetch + double-buffered LDS, one barrier per chunk (R6-proven).
// ---------------------------------------------------------------------------
#define PACKW1(B, c, x0, x1, csacc) do {                                      \
    unsigned u0 = __float_as_uint(x0), u1 = __float_as_uint(x1);              \
    unsigned packH = (u0 >> 16) | (u1 & 0xFFFF0000u);                         \
    float l0_ = 2.0f * ((x0) - __uint_as_float(u0 & 0xFFFF0000u));            \
    float l1_ = 2.0f * ((x1) - __uint_as_float(u1 & 0xFFFF0000u));            \
    unsigned packL = (unsigned)f2bf_rne(l0_) | ((unsigned)f2bf_rne(l1_) << 16); \
    int idx_ = (c) * GSTR + 2 * (p ^ (cg & 12));                              \
    *(unsigned*)&XT[B][0][idx_] = packH;                                      \
    *(unsigned*)&XT[B][1][idx_] = packL;                                      \
    csacc += (x0) + (x1);                                                     \
} while (0)

#define LOADR(ci, r0, r1, r2, r3) do {                                        \
    const float4* s4_ = (const float4*)x + ((size_t)(ci) * 32 + 2 * p) * 32 + cg * 2; \
    r0 = s4_[0]; r1 = s4_[1]; r2 = s4_[32]; r3 = s4_[33];                     \
} while (0)

#define PACKALL(B, r0, r1, r2, r3) do {                                       \
    PACKW1(B, cg * 8 + 0, r0.x, r2.x, cs0);                                   \
    PACKW1(B, cg * 8 + 1, r0.y, r2.y, cs1);                                   \
    PACKW1(B, cg * 8 + 2, r0.z, r2.z, cs2);                                   \
    PACKW1(B, cg * 8 + 3, r0.w, r2.w, cs3);                                   \
    PACKW1(B, cg * 8 + 4, r1.x, r3.x, cs4);                                   \
    PACKW1(B, cg * 8 + 5, r1.y, r3.y, cs5);                                   \
    PACKW1(B, cg * 8 + 6, r1.z, r3.z, cs6);                                   \
    PACKW1(B, cg * 8 + 7, r1.w, r3.w, cs7);                                   \
} while (0)

#define MFMA_STEP(B) do {                                                     \
    const unsigned short* Xh = &XT[B][0][0];                                  \
    const unsigned short* Xl = &XT[B][1][0];                                  \
    bf16x8 ah0 = ldfrag(Xh, (2 * w + 0) * 16 + lc, ls);                       \
    bf16x8 ah1 = ldfrag(Xh, (2 * w + 1) * 16 + lc, ls);                       \
    _Pragma("unroll")                                                         \
    for (int tj = 0; tj < 8; ++tj) {                                          \
        bf16x8 bh = ldfrag(Xh, tj * 16 + lc, ls);                             \
        bf16x8 bl = ldfrag(Xl, tj * 16 + lc, ls);                             \
        acc[0][tj] = __builtin_amdgcn_mfma_f32_16x16x32_bf16(ah0, bh, acc[0][tj], 0, 0, 0); \
        acc[0][tj] = __builtin_amdgcn_mfma_f32_16x16x32_bf16(ah0, bl, acc[0][tj], 0, 0, 0); \
        acc[1][tj] = __builtin_amdgcn_mfma_f32_16x16x32_bf16(ah1, bh, acc[1][tj], 0, 0, 0); \
        acc[1][tj] = __builtin_amdgcn_mfma_f32_16x16x32_bf16(ah1, bl, acc[1][tj], 0, 0, 0); \
    }                                                                         \
} while (0)

template <int STORE>
__global__ __launch_bounds__(256, 3) void k_gram(const float* __restrict__ x,
                                                 float* __restrict__ part,
                                                 float* __restrict__ colpart,
                                                 float* __restrict__ gram,
                                                 float* __restrict__ colsum,
                                                 int cpb) {
    __shared__ __align__(16) unsigned short XT[2][2][128 * GSTR];  // [buf][hi/lo]
    const int tid = threadIdx.x;
    const int w = tid >> 6;
    const int l = tid & 63;
    const int lc = l & 15;
    const int ls = (l >> 4) * 4;
    const int p = tid >> 4;          // row-pair (rows 2p,2p+1 of chunk)
    const int cg = tid & 15;         // channel-group (8 ch), lane-minor

    f32x4 acc[2][8];
#pragma unroll
    for (int a = 0; a < 2; ++a)
#pragma unroll
        for (int t = 0; t < 8; ++t) acc[a][t] = (f32x4){0.f, 0.f, 0.f, 0.f};
    float cs0 = 0.f, cs1 = 0.f, cs2 = 0.f, cs3 = 0.f;
    float cs4 = 0.f, cs5 = 0.f, cs6 = 0.f, cs7 = 0.f;

    const int c0 = blockIdx.x * cpb;
    float4 a0, a1, a2, a3, b0, b1, b2, b3;

    LOADR(c0 + 0, a0, a1, a2, a3);
    LOADR(c0 + 1, b0, b1, b2, b3);
    PACKALL(0, a0, a1, a2, a3);
    __syncthreads();

#pragma unroll 1
    for (int t = 0; t < cpb; t += 2) {
        MFMA_STEP(0);                         // chunk t
        PACKALL(1, b0, b1, b2, b3);           // chunk t+1 -> LDS[1]
        if (t + 2 < cpb) LOADR(c0 + t + 2, a0, a1, a2, a3);
        __syncthreads();
        MFMA_STEP(1);                         // chunk t+1
        if (t + 2 < cpb) {
            PACKALL(0, a0, a1, a2, a3);       // chunk t+2 -> LDS[0]
            if (t + 3 < cpb) LOADR(c0 + t + 3, b0, b1, b2, b3);
            __syncthreads();
        }
    }

    // intra-block colsum reduction (reuse XT as float LDS)
    __syncthreads();
    float* cls = (float*)&XT[0][0][0];        // 128 ch x 16 pairs
    cls[(cg * 8 + 0) * 16 + p] = cs0;
    cls[(cg * 8 + 1) * 16 + p] = cs1;
    cls[(cg * 8 + 2) * 16 + p] = cs2;
    cls[(cg * 8 + 3) * 16 + p] = cs3;
    cls[(cg * 8 + 4) * 16 + p] = cs4;
    cls[(cg * 8 + 5) * 16 + p] = cs5;
    cls[(cg * 8 + 6) * 16 + p] = cs6;
    cls[(cg * 8 + 7) * 16 + p] = cs7;
    __syncthreads();
    float csr = 0.f;
    if (tid < 128) {
#pragma unroll
        for (int pp = 0; pp < 16; ++pp) csr += cls[tid * 16 + pp];
    }

    if (STORE) {
        float* pb = part + (size_t)blockIdx.x * 16384;
#pragma unroll
        for (int a = 0; a < 2; ++a)
#pragma unroll
            for (int tj = 0; tj < 8; ++tj)
#pragma unroll
                for (int q = 0; q < 4; ++q) {
                    int row = (2 * w + a) * 16 + (l >> 4) * 4 + q;
                    int col = tj * 16 + lc;
                    pb[row * NCH + col] = acc[a][tj][q];
                }
        if (tid < 128) colpart[blockIdx.x * 128 + tid] = csr;
    } else {
#pragma unroll
        for (int a = 0; a < 2; ++a)
#pragma unroll
            for (int tj = 0; tj < 8; ++tj)
#pragma unroll
                for (int q = 0; q < 4; ++q) {
                    int row = (2 * w + a) * 16 + (l >> 4) * 4 + q;
                    int col = tj * 16 + lc;
                    atomicAdd(&gram[row * NCH + col], acc[a][tj][q]);
                }
        if (tid < 128) atomicAdd(&colsum[tid], csr);
    }
}

// ---------------------------------------------------------------------------
// Two-stage tree reduction of per-block partials (R7-proven).
// ---------------------------------------------------------------------------
__global__ __launch_bounds__(256) void k_reduce1(const float* __restrict__ part,
                                                 const float* __restrict__ colpart,
                                                 float* __restrict__ part2,
                                                 float* __restrict__ col2,
                                                 int NG) {
    const int b = blockIdx.x;
    if (b < 16 * NG) {
        const int g = b >> 4;
        const int sl = b & 15;
        const int e4 = sl * 1024 + threadIdx.x * 4;
        const float* p0 = part + (size_t)g * 32 * 16384 + e4;
        float4 s = {0.f, 0.f, 0.f, 0.f};
#pragma unroll
        for (int k = 0; k < 32; ++k) {
            float4 v = *(const float4*)(p0 + (size_t)k * 16384);
            s.x += v.x; s.y += v.y; s.z += v.z; s.w += v.w;
        }
        *(float4*)(part2 + (size_t)g * 16384 + e4) = s;
    } else {
        const int g = b - 16 * NG;
        if (threadIdx.x < 128) {
            const float* c0 = colpart + g * 32 * 128 + threadIdx.x;
            float s = 0.f;
#pragma unroll
            for (int k = 0; k < 32; ++k) s += c0[k * 128];
            col2[g * 128 + threadIdx.x] = s;
        }
    }
}

__global__ __launch_bounds__(256) void k_reduce2(const float* __restrict__ part2,
                                                 const float* __restrict__ col2,
                                                 float* __restrict__ gram,
                                                 float* __restrict__ colsum,
                                                 int NG) {
    const int b = blockIdx.x;
    if (b < 16) {
        const int e4 = b * 1024 + threadIdx.x * 4;
        float4 s = {0.f, 0.f, 0.f, 0.f};
#pragma unroll 8
        for (int g = 0; g < NG; ++g) {
            float4 v = *(const float4*)(part2 + (size_t)g * 16384 + e4);
            s.x += v.x; s.y += v.y; s.z += v.z; s.w += v.w;
        }
        *(float4*)(gram + e4) = s;
    } else if (threadIdx.x < 128) {
        float s = 0.f;
#pragma unroll 8
        for (int g = 0; g < NG; ++g) s += col2[g * 128 + threadIdx.x];
        colsum[threadIdx.x] = s;
    }
}

// ---------------------------------------------------------------------------
// k_chol: 4-pivot blocked Gauss-Jordan, 1024 threads, float4 LDS, rank-4
// trailing updates.  Per block kb: (phase 1) stage raw pivot rows kb..kb+3
// to Praw; (phase 2) every thread redundantly factors the 4x4 diag block,
// composes raw-basis coefficients c = f·T (T = unit-lower 4x4), applies
// row_j -= Σ_t c_t · Praw_t to B cols (groups <= kb/4) and A cols (groups
// >= kb/4+1).  Rows kb+1..kb+3 use truncated chains (tmax = j-kb).
// Exactly the rank-1 algebra, 2 barriers / 4 pivots.
// ---------------------------------------------------------------------------
__global__ __launch_bounds__(1024) void k_chol(const float* __restrict__ gram,
                                               const float* __restrict__ colsum,
                                               float* __restrict__ Wout,
                                               float* __restrict__ mout) {
    __shared__ float C[128][264];                 // [0..127]=B, [128..255]=A, 8 pad
    __shared__ __align__(16) float Praw[4][264];  // staged raw pivot rows
    __shared__ float m[128];
    __shared__ float dsq[128];
    const int tid = threadIdx.x;
    const int rs = tid >> 5;        // rowslot 0..31
    const int cs = tid & 31;        // colslot 0..31

    if (tid < 128) {
        m[tid] = colsum[tid] * (1.0f / (float)NROWS);
        mout[tid] = m[tid];
    }
    __syncthreads();
    for (int idx = tid; idx < 128 * 128; idx += 1024) {
        int i = idx >> 7, j = idx & 127;
        float g = 0.5f * (gram[i * NCH + j] + gram[j * NCH + i]);   // sym(G2)
        C[i][128 + j] = (g - (float)NROWS * m[i] * m[j]) * (1.0f / (float)(NROWS - 1));
        C[i][j] = (i == j) ? 1.0f : 0.0f;
    }
    __syncthreads();

#pragma unroll 1
    for (int kb = 0; kb < 128; kb += 4) {
        // phase 1: stage raw pivot rows (264 float4 copies)
        if (tid < 264) {
            int r = tid / 66, g = tid % 66;
            *(float4*)&Praw[r][g * 4] = *(const float4*)&C[kb + r][g * 4];
        }
        __syncthreads();

        // redundant 4x4 factorization (same-address broadcast reads)
        float M00 = C[kb + 0][128 + kb + 0], M01 = C[kb + 0][128 + kb + 1];
        float M02 = C[kb + 0][128 + kb + 2], M03 = C[kb + 0][128 + kb + 3];
        float M10 = C[kb + 1][128 + kb + 0], M11 = C[kb + 1][128 + kb + 1];
        float M12 = C[kb + 1][128 + kb + 2], M13 = C[kb + 1][128 + kb + 3];
        float M20 = C[kb + 2][128 + kb + 0], M21 = C[kb + 2][128 + kb + 1];
        float M22 = C[kb + 2][128 + kb + 2], M23 = C[kb + 2][128 + kb + 3];
        float M30 = C[kb + 3][128 + kb + 0], M31 = C[kb + 3][128 + kb + 1];
        float M32 = C[kb + 3][128 + kb + 2], M33 = C[kb + 3][128 + kb + 3];

        float rd0 = 1.0f / M00;
        float g10 = M10 * rd0, g20 = M20 * rd0, g30 = M30 * rd0;
        float N11 = M11 - g10 * M01, N12 = M12 - g10 * M02, N13 = M13 - g10 * M03;
        float N21 = M21 - g20 * M01, N22 = M22 - g20 * M02, N23 = M23 - g20 * M03;
        float N31 = M31 - g30 * M01, N32 = M32 - g30 * M02, N33 = M33 - g30 * M03;
        float rd1 = 1.0f / N11;
        float g21 = N21 * rd1, g31 = N31 * rd1;
        float P22 = N22 - g21 * N12, P23 = N23 - g21 * N13;
        float P32 = N32 - g31 * N12, P33 = N33 - g31 * N13;
        float rd2 = 1.0f / P22;
        float g32 = P32 * rd2;
        float Q33 = P33 - g32 * P23;
        float rd3 = 1.0f / Q33;

        float T10 = -g10;
        float T20 = -g20 - g21 * T10, T21 = -g21;
        float T30 = -g30 - g31 * T10 - g32 * T20;
        float T31 = -g31 - g32 * T21;
        float T32 = -g32;

        if (tid == 0) {
            dsq[kb + 0] = 1.0f / sqrtf(M00);
            dsq[kb + 1] = 1.0f / sqrtf(N11);
            dsq[kb + 2] = 1.0f / sqrtf(P22);
            dsq[kb + 3] = 1.0f / sqrtf(Q33);
        }

        const bool doB = (cs <= (kb >> 2));
        const int gRel = (kb >> 2) + 1 + cs;    // A-region group index
        const bool doA = (gRel < 32);

        float4 Pb0, Pb1, Pb2, Pb3, Pa0, Pa1, Pa2, Pa3;
        if (doB) {
            Pb0 = *(const float4*)&Praw[0][cs * 4];
            Pb1 = *(const float4*)&Praw[1][cs * 4];
            Pb2 = *(const float4*)&Praw[2][cs * 4];
            Pb3 = *(const float4*)&Praw[3][cs * 4];
        }
        if (doA) {
            Pa0 = *(const float4*)&Praw[0][128 + gRel * 4];
            Pa1 = *(const float4*)&Praw[1][128 + gRel * 4];
            Pa2 = *(const float4*)&Praw[2][128 + gRel * 4];
            Pa3 = *(const float4*)&Praw[3][128 + gRel * 4];
        }

        for (int j = kb + 1 + rs; j < 128; j += 32) {
            const int tmax = j - kb;            // >=4 for non-pivot rows
            float a0 = C[j][128 + kb + 0], a1 = C[j][128 + kb + 1];
            float a2 = C[j][128 + kb + 2], a3 = C[j][128 + kb + 3];
            float f0 = a0 * rd0;
            float c0 = f0, c1 = 0.f, c2 = 0.f, c3 = 0.f;
            if (tmax > 1) {
                float f1 = (a1 - c0 * M01) * rd1;
                c0 += f1 * T10; c1 = f1;
                if (tmax > 2) {
                    float f2 = (a2 - c0 * M02 - c1 * M12) * rd2;
                    c0 += f2 * T20; c1 += f2 * T21; c2 = f2;
                    if (tmax > 3) {
                        float f3 = (a3 - c0 * M03 - c1 * M13 - c2 * M23) * rd3;
                        c0 += f3 * T30; c1 += f3 * T31; c2 += f3 * T32; c3 = f3;
                    }
                }
            }
            if (doB) {
                float4 v = *(const float4*)&C[j][cs * 4];
                v.x -= c0 * Pb0.x + c1 * Pb1.x + c2 * Pb2.x + c3 * Pb3.x;
                v.y -= c0 * Pb0.y + c1 * Pb1.y + c2 * Pb2.y + c3 * Pb3.y;
                v.z -= c0 * Pb0.z + c1 * Pb1.z + c2 * Pb2.z + c3 * Pb3.z;
                v.w -= c0 * Pb0.w + c1 * Pb1.w + c2 * Pb2.w + c3 * Pb3.w;
                *(float4*)&C[j][cs * 4] = v;
            }
            if (doA) {
                float4 v = *(const float4*)&C[j][128 + gRel * 4];
                v.x -= c0 * Pa0.x + c1 * Pa1.x + c2 * Pa2.x + c3 * Pa3.x;
                v.y -= c0 * Pa0.y + c1 * Pa1.y + c2 * Pa2.y + c3 * Pa3.y;
                v.z -= c0 * Pa0.z + c1 * Pa1.z + c2 * Pa2.z + c3 * Pa3.z;
                v.w -= c0 * Pa0.w + c1 * Pa1.w + c2 * Pa2.w + c3 * Pa3.w;
                *(float4*)&C[j][128 + gRel * 4] = v;
            }
        }
        __syncthreads();
    }

    for (int idx = tid; idx < 128 * 128; idx += 1024) {
        int j = idx >> 7, c = idx & 127;
        float vv = (c < j) ? C[j][c] * dsq[j] : ((c == j) ? dsq[j] : 0.0f);
        Wout[idx] = vv;
    }
}

// ---------------------------------------------------------------------------
// k_apply: out = xn + bf16(xn) @ R^T, R = W - I (unchanged, healthy).
// ---------------------------------------------------------------------------
__global__ __launch_bounds__(256, 3) void k_apply(const float* __restrict__ x,
                                                  const float* __restrict__ Wg,
                                                  const float* __restrict__ mg,
                                                  float* __restrict__ out) {
    __shared__ __align__(16) unsigned char XS[128 * 128];
    __shared__ float msh[128];
    const int tid = threadIdx.x;
    const int w = tid >> 6, l = tid & 63;
    const int lc = l & 15, la = l >> 4;

    if (tid < 32) *(float4*)&msh[tid * 4] = *(const float4*)&mg[tid * 4];
    __syncthreads();

    bf16x8 rfrag[2][4];
#pragma unroll
    for (int tjl = 0; tjl < 2; ++tjl) {
        int j = (w * 2 + tjl) * 16 + lc;
#pragma unroll
        for (int ks = 0; ks < 4; ++ks) {
            int i0 = ks * 32 + la * 8;
            float4 wa = *(const float4*)&Wg[j * 128 + i0];
            float4 wb = *(const float4*)&Wg[j * 128 + i0 + 4];
            rfrag[tjl][ks][0] = f2bf_rne(wa.x - ((j == i0 + 0) ? 1.0f : 0.0f));
            rfrag[tjl][ks][1] = f2bf_rne(wa.y - ((j == i0 + 1) ? 1.0f : 0.0f));
            rfrag[tjl][ks][2] = f2bf_rne(wa.z - ((j == i0 + 2) ? 1.0f : 0.0f));
            rfrag[tjl][ks][3] = f2bf_rne(wa.w - ((j == i0 + 3) ? 1.0f : 0.0f));
            rfrag[tjl][ks][4] = f2bf_rne(wb.x - ((j == i0 + 4) ? 1.0f : 0.0f));
            rfrag[tjl][ks][5] = f2bf_rne(wb.y - ((j == i0 + 5) ? 1.0f : 0.0f));
            rfrag[tjl][ks][6] = f2bf_rne(wb.z - ((j == i0 + 6) ? 1.0f : 0.0f));
            rfrag[tjl][ks][7] = f2bf_rne(wb.w - ((j == i0 + 7) ? 1.0f : 0.0f));
        }
    }

    f32x4 acc[8][2];
#pragma unroll
    for (int ti = 0; ti < 8; ++ti)
#pragma unroll
        for (int tjl = 0; tjl < 2; ++tjl) acc[ti][tjl] = (f32x4){0.f, 0.f, 0.f, 0.f};

    const size_t rowbase = (size_t)blockIdx.x * 128;

#pragma unroll
    for (int c = 0; c < 2; ++c) {
        const int kb = c * 64;
#pragma unroll
        for (int rep = 0; rep < 8; ++rep) {
            int f = tid + 256 * rep;
            int r = f >> 4, i4 = f & 15;
            float4 vx = *(const float4*)&x[(rowbase + r) * 128 + kb + i4 * 4];
            float4 mv = *(const float4*)&msh[kb + i4 * 4];
            unsigned b0 = f2bf_rne(vx.x - mv.x);
            unsigned b1 = f2bf_rne(vx.y - mv.y);
            unsigned b2 = f2bf_rne(vx.z - mv.z);
            unsigned b3 = f2bf_rne(vx.w - mv.w);
            unsigned off = r * 128 + ((((i4 >> 1) ^ (r & 7))) << 4) + (i4 & 1) * 8;
            *(uint2*)(XS + off) = make_uint2(b0 | (b1 << 16), b2 | (b3 << 16));
        }
        __syncthreads();
#pragma unroll
        for (int ksl = 0; ksl < 2; ++ksl) {
#pragma unroll
            for (int ti = 0; ti < 8; ++ti) {
                int r = ti * 16 + lc;
                int g = ksl * 4 + la;
                bf16x8 af = *(const bf16x8*)(XS + r * 128 + ((g ^ (r & 7)) << 4));
                acc[ti][0] = __builtin_amdgcn_mfma_f32_16x16x32_bf16(af, rfrag[0][c * 2 + ksl], acc[ti][0], 0, 0, 0);
                acc[ti][1] = __builtin_amdgcn_mfma_f32_16x16x32_bf16(af, rfrag[1][c * 2 + ksl], acc[ti][1], 0, 0, 0);
            }
        }
        __syncthreads();
    }

#pragma unroll
    for (int ti = 0; ti < 8; ++ti)
#pragma unroll
        for (int tjl = 0; tjl < 2; ++tjl)
#pragma unroll
            for (int q = 0; q < 4; ++q) {
                int rloc = ti * 16 + la * 4 + q;
                int cglob = (w * 2 + tjl) * 16 + lc;
                size_t a = (rowbase + rloc) * 128 + cglob;
                out[a] = (x[a] - msh[cglob]) + acc[ti][tjl][q];
            }
}

extern "C" void kernel_launch(void* const* d_in, const int* in_sizes, int n_in,
                              void* d_out, int out_size, void* d_ws, size_t ws_size,
                              hipStream_t stream) {
    const float* x = (const float*)d_in[0];
    float* ws = (float*)d_ws;
    float* gram = ws;                  // 16384
    float* colsum = ws + 16384;        // 128
    float* W = ws + 16512;             // 16384
    float* m = ws + 32896;             // 128
    float* colpart = ws + 40960;       // up to 1024*128
    float* part = ws + 172032;         // nP*16384
    float* out = (float*)d_out;

    int nP = 0;
    for (int cand = 1024; cand >= 256; cand >>= 1) {
        int ng = cand / 32;
        size_t need = ((size_t)172032 + (size_t)cand * 16384 +
                       (size_t)ng * 16384 + (size_t)ng * 128) * sizeof(float);
        if (ws_size >= need) { nP = cand; break; }
    }

    if (nP > 0) {
        const int NG = nP / 32;
        float* part2 = part + (size_t)nP * 16384;
        float* col2 = part2 + (size_t)NG * 16384;
        int cpb = 16384 / nP;
        k_gram<1><<<nP, 256, 0, stream>>>(x, part, colpart, gram, colsum, cpb);
        k_reduce1<<<16 * NG + NG, 256, 0, stream>>>(part, colpart, part2, col2, NG);
        k_reduce2<<<17, 256, 0, stream>>>(part2, col2, gram, colsum, NG);
    } else {
        hipMemsetAsync(d_ws, 0, (16384 + 128) * sizeof(float), stream);
        k_gram<0><<<512, 256, 0, stream>>>(x, part, colpart, gram, colsum, 32);
    }
    k_chol<<<1, 1024, 0, stream>>>(gram, colsum, W, m);
    k_apply<<<NROWS / 128, 256, 0, stream>>>(x, W, m, out);
}